// Round 8
// baseline (2474.957 us; speedup 1.0000x reference)
//
#include <hip/hip_runtime.h>

#ifndef __has_builtin
#define __has_builtin(x) 0
#endif

__device__ __forceinline__ float fexp2(float x) {
#if __has_builtin(__builtin_amdgcn_exp2f)
  return __builtin_amdgcn_exp2f(x);   // v_exp_f32 (2^x)
#else
  return exp2f(x);
#endif
}
__device__ __forceinline__ float flog2(float x) {
#if __has_builtin(__builtin_amdgcn_logf)
  return __builtin_amdgcn_logf(x);    // v_log_f32 (log2)
#else
  return log2f(x);
#endif
}

typedef float  f32x4  __attribute__((ext_vector_type(4)));
typedef unsigned int u32x4 __attribute__((ext_vector_type(4)));
typedef short  short8 __attribute__((ext_vector_type(8)));

namespace {
constexpr int NPTS = 2048;
constexpr int HALF = 1024;          // sources per WG (half-split)
constexpr int NPROB = 24;           // 8 batches x {xy, xx, yy}
constexpr int WGS_PER_PROB = 64;    // 32 row-blocks x 2 source-halves
constexpr int THREADS = 256;        // 4 waves x 16 rows each
constexpr int NPASS = 100;          // 50 Sinkhorn iters x 2 half-passes
constexpr float KS  = 1.44269504088896340736f / 0.0025f;   // log2(e)/eps
constexpr float HKS = 0.5f * KS;
constexpr float NEG_EPS_LN2 = -0.0025f * 0.69314718055994530942f; // -eps*ln2
constexpr float LOG2N = 11.0f;                             // log2(2048)
}

// 3-way F16 split: v == h + m + l EXACTLY for any f32 v in f16 range.
__device__ __forceinline__ void split3h(float v, float& h, float& m, float& l) {
  h = (float)(_Float16)v;    // RTN f16
  float r1 = v - h;          // exact in f32
  m = (float)(_Float16)r1;
  l = r1 - m;                // exact (f16-representable up to subnormal tail)
}
// pack two f32 values as f16 into one VGPR: a -> k-even (low16), b -> k-odd.
__device__ __forceinline__ unsigned pkh(float a, float b) {
  unsigned short ab = __builtin_bit_cast(unsigned short, (_Float16)a);
  unsigned short bb = __builtin_bit_cast(unsigned short, (_Float16)b);
  return (unsigned)ab | ((unsigned)bb << 16);
}

// MFMA pass. WG (p, blk, h): 64 target rows (4 waves x 16), partial LSE
// over sources j in [1024h, 1024h+1024).
//   exp-arg(r,j) = KS*t_r.s_j + A_j + B_r - Amax   (<= 0 a-priori + ~1e-5 slop)
//   A_j = KS*phi_j - HKS|s_j|^2, B_r = -HKS|t_r|^2, Amax = max_j(KS*phi_j).
// *** SCALING FIX (round-8): KS rides on the SOURCE side only. ***
// A-operand = 3-way f16 split of RAW t (<=1); B-operand = split of KS*s
// (<=577). Round 4-7 split KS*t on BOTH sides -> MFMA computed KS^2*t.s:
// round 4's NaN (exp overflow, no clamp) and rounds 5-7's identical
// dtype-independent 1.44e-3 (clamp-stabilized wrong dynamics) both trace
// to this one line. Products now <=577 (round-3 scale). Dropped ml/lm/ll
// cross terms <= ~1e-7 log2-units (target residuals are of 1.0).
// Dot via mfma_f32_16x16x32_f16, 21 used k-slots (hh,hm,mh,hl,mm,lh per
// axis + exact A ride-along on k18-20, A-side 1.0). C operand = Bp.
// Layouts (gfx950): A row=l&15; B col=l&15; D col=l&15 row=4*(l>>4)+reg
// [measured m89; k-map shared by A/B so pairing is permutation-immune].
// Stored partials: contract LSE_half - B_r = m + log2(s), m = Amax - B_r.
__global__ void __launch_bounds__(THREADS, 3) sink_mfma(
    const float* __restrict__ p1, const float* __restrict__ p2,
    float* __restrict__ fm, float* __restrict__ fs,
    float* __restrict__ gm, float* __restrict__ gs, int t)
{
  // per source 48B: u32x4[3] = k-blocks 0..2 (k-block 3 all-zero tile at end)
  __shared__ u32x4 Bfr[HALF * 3 + 1];
  __shared__ float wmax[4];

  const int w   = blockIdx.x;
  const int p   = w >> 6;           // problem 0..23
  const int r_  = w & 63;
  const int blk = r_ & 31;          // row-block (64 rows)
  const int h   = r_ >> 5;          // source half 0/1
  const int b    = p / 3;
  const int kind = p - 3 * b;       // 0: xy, 1: xx, 2: yy
  const float* X = (kind == 2 ? p2 : p1) + b * (NPTS * 3);
  const float* Y = (kind == 1 ? p1 : p2) + b * (NPTS * 3);

  const bool even = (t & 1) == 0;
  const float* tgt = even ? X : Y;
  const float* src = even ? Y : X;
  const float* pmA = even ? gm : fm;
  const float* psA = even ? gs : fs;
  float* omA = even ? fm : gm;
  float* osA = even ? fs : gs;

  const int tid  = threadIdx.x;
  const int lane = tid & 63;
  const int wv   = tid >> 6;        // wave 0..3
  const int l15  = lane & 15;
  const int kb   = lane >> 4;       // k-block this lane supplies

  // ---- stage sources: merge prev half-partials -> A_j; build B-frags ----
  float am = -1e30f;
  #pragma unroll
  for (int i = 0; i < HALF / THREADS; ++i) {
    int jl = tid + THREADS * i;
    int jg = HALF * h + jl;
    float sx = src[3 * jg + 0], sy = src[3 * jg + 1], sz = src[3 * jg + 2];
    float q2 = HKS * (sx * sx + sy * sy + sz * sz);
    float A;
    if (t == 0) {
      A = -q2;
    } else {
      float m0 = pmA[(p * 2 + 0) * NPTS + jg];
      float m1 = pmA[(p * 2 + 1) * NPTS + jg];
      float c0 = psA[(p * 2 + 0) * NPTS + jg];
      float c1 = psA[(p * 2 + 1) * NPTS + jg];
      float M = fmaxf(m0, m1);
      float S = fmaf(c0, fexp2(m0 - M), c1 * fexp2(m1 - M));
      A = LOG2N - M - flog2(fmaxf(S, 1e-38f));   // = KS*phi_j - HKS|s_j|^2
    }
    am = fmaxf(am, A + q2);          // = KS*phi_j (t==0: exactly 0)
    float hx, mx, lx, hy, my, ly, hz, mz, lz, Ah, Am, Al;
    split3h(KS * sx, hx, mx, lx);    // SOURCE carries the KS scale
    split3h(KS * sy, hy, my, ly);
    split3h(KS * sz, hz, mz, lz);
    split3h(A, Ah, Am, Al);          // exact: A == Ah+Am+Al
    Bfr[jl * 3 + 0] = (u32x4){pkh(hx, mx), pkh(hx, lx), pkh(mx, hx), pkh(hy, my)};
    Bfr[jl * 3 + 1] = (u32x4){pkh(hy, ly), pkh(my, hy), pkh(hz, mz), pkh(hz, lz)};
    Bfr[jl * 3 + 2] = (u32x4){pkh(mz, hz), pkh(Ah, Am), pkh(Al, 0.f), 0u};
  }
  if (tid == 0) Bfr[HALF * 3] = (u32x4){0u, 0u, 0u, 0u};

  #pragma unroll
  for (int off = 1; off <= 32; off <<= 1) am = fmaxf(am, __shfl_xor(am, off));
  if (lane == 0) wmax[wv] = am;

  // ---- per-lane A-frag: RAW target coords (fix: no KS here) ----
  const int rowbase = blk * 64 + wv * 16;
  const int r = rowbase + l15;
  float tx = tgt[3 * r + 0], ty = tgt[3 * r + 1], tz = tgt[3 * r + 2];
  float hx, mx, lx, hy, my, ly, hz, mz, lz;
  split3h(tx, hx, mx, lx);
  split3h(ty, hy, my, ly);
  split3h(tz, hz, mz, lz);
  unsigned a0, a1, a2, a3;
  if (kb == 0)      { a0 = pkh(hx, hx); a1 = pkh(mx, hx); a2 = pkh(mx, lx); a3 = pkh(hy, hy); }
  else if (kb == 1) { a0 = pkh(my, hy); a1 = pkh(my, ly); a2 = pkh(hz, hz); a3 = pkh(mz, hz); }
  else if (kb == 2) { a0 = pkh(mz, lz); a1 = pkh(1.f, 1.f); a2 = pkh(1.f, 0.f); a3 = 0u; }
  else              { a0 = 0u; a1 = 0u; a2 = 0u; a3 = 0u; }
  const short8 afrag = __builtin_bit_cast(short8, (u32x4){a0, a1, a2, a3});
  const float Bv = -HKS * (tx * tx + ty * ty + tz * tz);

  __syncthreads();

  const float Amax = fmaxf(fmaxf(wmax[0], wmax[1]), fmaxf(wmax[2], wmax[3]));
  // C operand: per-lane constant Bp_q = B(row kb*4+q) - Amax
  const float Bp0 = __shfl(Bv, kb * 4 + 0) - Amax;
  const float Bp1 = __shfl(Bv, kb * 4 + 1) - Amax;
  const float Bp2 = __shfl(Bv, kb * 4 + 2) - Amax;
  const float Bp3 = __shfl(Bv, kb * 4 + 3) - Amax;
  const f32x4 cin = {Bp0, Bp1, Bp2, Bp3};

  // ---- tile loop: 64 tiles of 16 sources ----
  const u32x4* bptr = Bfr + (kb < 3 ? (l15 * 3 + kb) : HALF * 3);
  const int bstride = (kb < 3) ? 48 : 0;   // u32x4 elems per 16-source tile
  float s0 = 0.f, s1 = 0.f, s2 = 0.f, s3 = 0.f;

  #pragma unroll 4
  for (int tile = 0; tile < HALF / 16; ++tile) {
    u32x4 braw = *bptr; bptr += bstride;
    short8 bfrag = __builtin_bit_cast(short8, braw);
    f32x4 d = __builtin_amdgcn_mfma_f32_16x16x32_f16(afrag, bfrag, cin, 0, 0, 0);
    // legit d <= ~+1e-5 (split slop); clamp is inert insurance
    s0 += fexp2(fminf(d.x, 0.25f));
    s1 += fexp2(fminf(d.y, 0.25f));
    s2 += fexp2(fminf(d.z, 0.25f));
    s3 += fexp2(fminf(d.w, 0.25f));
  }

  // ---- reduce across the 16 col-lanes (same m̂ -> pure adds) ----
  #pragma unroll
  for (int off = 1; off <= 8; off <<= 1) {
    s0 += __shfl_xor(s0, off);
    s1 += __shfl_xor(s1, off);
    s2 += __shfl_xor(s2, off);
    s3 += __shfl_xor(s3, off);
  }

  // ---- store partials: m(row kb*4+q) = Amax - B_row = -Bp_q ----
  if (l15 == 0) {
    float* om = omA + (p * 2 + h) * NPTS;
    float* os = osA + (p * 2 + h) * NPTS;
    int r0 = rowbase + kb * 4;
    om[r0 + 0] = -Bp0; os[r0 + 0] = s0;
    om[r0 + 1] = -Bp1; os[r0 + 1] = s1;
    om[r0 + 2] = -Bp2; os[r0 + 2] = s2;
    om[r0 + 3] = -Bp3; os[r0 + 3] = s3;
  }
}

// ROUND-3-PROVEN final reduction: single 1024-thread WG, deterministic
// double tree over the 98304 (side,problem,row) values.
__global__ void __launch_bounds__(1024) sink_finalize(
    const float* __restrict__ fm, const float* __restrict__ fs,
    const float* __restrict__ gm, const float* __restrict__ gs,
    const float* __restrict__ p1, const float* __restrict__ p2,
    float* __restrict__ out)
{
  __shared__ double red[1024];
  const int tid = threadIdx.x;
  const int PER_SIDE = NPROB * NPTS;     // 49152
  const int TOT = 2 * PER_SIDE;
  double acc = 0.0;
  for (int idx = tid; idx < TOT; idx += 1024) {
    int side = idx >= PER_SIDE;          // 0: f (rows of X), 1: g (rows of Y)
    int rem  = idx - side * PER_SIDE;
    int p = rem >> 11;
    int i = rem & (NPTS - 1);
    const float* mA = side ? gm : fm;
    const float* sA = side ? gs : fs;
    float m0 = mA[(p * 2 + 0) * NPTS + i], m1 = mA[(p * 2 + 1) * NPTS + i];
    float c0 = sA[(p * 2 + 0) * NPTS + i], c1 = sA[(p * 2 + 1) * NPTS + i];
    float M = fmaxf(m0, m1);
    float S = fmaf(c0, fexp2(m0 - M), c1 * fexp2(m1 - M));
    int b = p / 3, kd = p - 3 * b;
    const float* rows = side ? (kd == 1 ? p1 : p2) : (kd == 2 ? p2 : p1);
    const float* pt = rows + b * (NPTS * 3) + 3 * i;
    float B = -HKS * (pt[0] * pt[0] + pt[1] * pt[1] + pt[2] * pt[2]);
    float val = NEG_EPS_LN2 * (M + B + flog2(fmaxf(S, 1e-38f)) - LOG2N);
    double wgt = (kd == 0) ? 1.0 : -0.5;
    acc += wgt * (double)val;
  }
  red[tid] = acc;
  __syncthreads();
  for (int st = 512; st > 0; st >>= 1) {
    if (tid < st) red[tid] += red[tid + st];
    __syncthreads();
  }
  if (tid == 0) out[0] = (float)(red[0] / (8.0 * 2048.0));
}

extern "C" void kernel_launch(void* const* d_in, const int* in_sizes, int n_in,
                              void* d_out, int out_size, void* d_ws, size_t ws_size,
                              hipStream_t stream)
{
  const float* p1 = (const float*)d_in[0];   // pcs1 [8,2048,3] f32
  const float* p2 = (const float*)d_in[1];   // pcs2 [8,2048,3] f32
  // workspace: 4 arrays of [24][2][2048] floats (m,s half-partials for f,g)
  float* fm = (float*)d_ws;
  float* fs = fm + NPROB * 2 * NPTS;
  float* gm = fs + NPROB * 2 * NPTS;
  float* gs = gm + NPROB * 2 * NPTS;

  for (int t = 0; t < NPASS; ++t) {
    sink_mfma<<<dim3(NPROB * WGS_PER_PROB), dim3(THREADS), 0, stream>>>(
        p1, p2, fm, fs, gm, gs, t);
  }
  sink_finalize<<<dim3(1), dim3(1024), 0, stream>>>(fm, fs, gm, gs, p1, p2,
                                                    (float*)d_out);
}

// Round 9
// 2049.472 us; speedup vs baseline: 1.2076x; 1.2076x over previous
//
#include <hip/hip_runtime.h>

#ifndef __has_builtin
#define __has_builtin(x) 0
#endif

__device__ __forceinline__ float fexp2(float x) {
#if __has_builtin(__builtin_amdgcn_exp2f)
  return __builtin_amdgcn_exp2f(x);   // v_exp_f32 (2^x)
#else
  return exp2f(x);
#endif
}
__device__ __forceinline__ float flog2(float x) {
#if __has_builtin(__builtin_amdgcn_logf)
  return __builtin_amdgcn_logf(x);    // v_log_f32 (log2)
#else
  return log2f(x);
#endif
}

typedef float    f32x4 __attribute__((ext_vector_type(4)));
typedef unsigned int u32x2 __attribute__((ext_vector_type(2)));
typedef unsigned int u32x4 __attribute__((ext_vector_type(4)));
typedef _Float16 f16x4 __attribute__((ext_vector_type(4)));

__device__ __forceinline__ f32x4 mfma16x16x16(f16x4 a, f16x4 b, f32x4 c) {
#if __has_builtin(__builtin_amdgcn_mfma_f32_16x16x16_f16)
  return __builtin_amdgcn_mfma_f32_16x16x16_f16(a, b, c, 0, 0, 0);
#else
  return __builtin_amdgcn_mfma_f32_16x16x16f16(a, b, c, 0, 0, 0);
#endif
}

namespace {
constexpr int NPTS = 2048;
constexpr int HALF = 1024;          // sources per WG (half-split)
constexpr int NPROB = 24;           // 8 batches x {xy, xx, yy}
constexpr int WGS_PER_PROB = 64;    // 32 row-blocks x 2 source-halves
constexpr int THREADS = 256;        // 4 waves x 16 rows each
constexpr int NPASS = 100;          // 50 Sinkhorn iters x 2 half-passes
constexpr float KS  = 1.44269504088896340736f / 0.0025f;   // log2(e)/eps
constexpr float HKS = 0.5f * KS;
constexpr float NEG_EPS_LN2 = -0.0025f * 0.69314718055994530942f; // -eps*ln2
constexpr float LOG2N = 11.0f;                             // log2(2048)
}

// 2-way f16 split: v ~= h + m, residual <= 2^-24|v| (dropped).
__device__ __forceinline__ void split2h(float v, float& h, float& m) {
  h = (float)(_Float16)v;
  m = (float)(_Float16)(v - h);
}
// 3-way f16 split: v == h + m + l EXACTLY (11+11+2 bits cover f32's 24).
__device__ __forceinline__ void split3h(float v, float& h, float& m, float& l) {
  h = (float)(_Float16)v;
  float r1 = v - h;
  m = (float)(_Float16)r1;
  l = r1 - m;
}
// pack two f32 as f16 into one VGPR: a -> k-even (low16), b -> k-odd.
__device__ __forceinline__ unsigned pkh(float a, float b) {
  unsigned short ab = __builtin_bit_cast(unsigned short, (_Float16)a);
  unsigned short bb = __builtin_bit_cast(unsigned short, (_Float16)b);
  return (unsigned)ab | ((unsigned)bb << 16);
}

// MFMA pass (K=16 repack). WG (p, blk, h): 64 target rows (4 waves x 16),
// partial LSE over sources j in [1024h, 1024h+1024).
//   exp-arg(r,j) = t_r.(KS*s_j) + A_j + B_r - Amax   (<= 0 a-priori + ~2e-4 slop)
//   A_j = KS*phi_j - HKS|s_j|^2, B_r = -HKS|t_r|^2, Amax = max_j(KS*phi_j).
// KS on the SOURCE side only (round-8 fix). mfma_f32_16x16x16_f16, 15 slots:
//   kb0 x: th*sh, th*sm, tm*sh, tm*sm   (t 2-way raw<=1, s 2-way KS-scaled)
//   kb1 y: same   kb2 z: same           kb3: 1*Ah, 1*Am, 1*Al, 0 (A exact)
// Dropped l-terms <= ~7e-5/coord log2-units -> final ~4e-6 (threshold 2.9e-5;
// round-8 K=32 exact-split version passed with absmax 0.0, ample margin).
// B-frag 32B/source: all 4 kb-lanes read real data, ds_read_b64 per tile,
// wave reads 512B/tile = exactly the unique data (vs 1KB with 1/4 zeros at
// K=32) -> LDS traffic halves; LDS 32KB -> 4 WG/CU (was 3).
// Layouts (gfx950): A row=l&15; B col=l&15; shared k-map so pairing is
// permutation-immune; D col=l&15 row=4*(l>>4)+reg [m89, shape-determined].
// Stored partials: contract LSE_half - B_r = m + log2(s), m = Amax - B_r.
__global__ void __launch_bounds__(THREADS, 4) sink_mfma(
    const float* __restrict__ p1, const float* __restrict__ p2,
    float* __restrict__ fm, float* __restrict__ fs,
    float* __restrict__ gm, float* __restrict__ gs, int t)
{
  // per source 32B = 2 x u32x4: [kb0 | kb1] and [kb2 | kb3]
  __shared__ u32x4 Bfr[HALF * 2];
  __shared__ float wmax[4];

  const int w   = blockIdx.x;
  const int p   = w >> 6;           // problem 0..23
  const int r_  = w & 63;
  const int blk = r_ & 31;          // row-block (64 rows)
  const int h   = r_ >> 5;          // source half 0/1
  const int b    = p / 3;
  const int kind = p - 3 * b;       // 0: xy, 1: xx, 2: yy
  const float* X = (kind == 2 ? p2 : p1) + b * (NPTS * 3);
  const float* Y = (kind == 1 ? p1 : p2) + b * (NPTS * 3);

  const bool even = (t & 1) == 0;
  const float* tgt = even ? X : Y;
  const float* src = even ? Y : X;
  const float* pmA = even ? gm : fm;
  const float* psA = even ? gs : fs;
  float* omA = even ? fm : gm;
  float* osA = even ? fs : gs;

  const int tid  = threadIdx.x;
  const int lane = tid & 63;
  const int wv   = tid >> 6;        // wave 0..3
  const int l15  = lane & 15;
  const int kb   = lane >> 4;       // k-block this lane supplies

  // ---- stage sources: merge prev half-partials -> A_j; build B-frags ----
  float am = -1e30f;
  #pragma unroll
  for (int i = 0; i < HALF / THREADS; ++i) {
    int jl = tid + THREADS * i;
    int jg = HALF * h + jl;
    float sx = src[3 * jg + 0], sy = src[3 * jg + 1], sz = src[3 * jg + 2];
    float q2 = HKS * (sx * sx + sy * sy + sz * sz);
    float A;
    if (t == 0) {
      A = -q2;
    } else {
      float m0 = pmA[(p * 2 + 0) * NPTS + jg];
      float m1 = pmA[(p * 2 + 1) * NPTS + jg];
      float c0 = psA[(p * 2 + 0) * NPTS + jg];
      float c1 = psA[(p * 2 + 1) * NPTS + jg];
      float M = fmaxf(m0, m1);
      float S = fmaf(c0, fexp2(m0 - M), c1 * fexp2(m1 - M));
      A = LOG2N - M - flog2(fmaxf(S, 1e-38f));   // = KS*phi_j - HKS|s_j|^2
    }
    am = fmaxf(am, A + q2);          // = KS*phi_j (t==0: exactly 0)
    float shx, smx, shy, smy, shz, smz, Ah, Am, Al;
    split2h(KS * sx, shx, smx);      // SOURCE carries the KS scale
    split2h(KS * sy, shy, smy);
    split2h(KS * sz, shz, smz);
    split3h(A, Ah, Am, Al);          // exact: A == Ah+Am+Al
    unsigned wx = pkh(shx, smx), wy = pkh(shy, smy), wz = pkh(shz, smz);
    Bfr[jl * 2 + 0] = (u32x4){wx, wx, wy, wy};             // kb0 | kb1
    Bfr[jl * 2 + 1] = (u32x4){wz, wz, pkh(Ah, Am), pkh(Al, 0.f)}; // kb2 | kb3
  }

  #pragma unroll
  for (int off = 1; off <= 32; off <<= 1) am = fmaxf(am, __shfl_xor(am, off));
  if (lane == 0) wmax[wv] = am;

  // ---- per-lane A-frag: RAW target coords, 2-way split ----
  const int rowbase = blk * 64 + wv * 16;
  const int r = rowbase + l15;
  float tx = tgt[3 * r + 0], ty = tgt[3 * r + 1], tz = tgt[3 * r + 2];
  float thx, tmx, thy, tmy, thz, tmz;
  split2h(tx, thx, tmx);
  split2h(ty, thy, tmy);
  split2h(tz, thz, tmz);
  u32x2 areg;
  if (kb == 0)      { areg = (u32x2){pkh(thx, thx), pkh(tmx, tmx)}; }
  else if (kb == 1) { areg = (u32x2){pkh(thy, thy), pkh(tmy, tmy)}; }
  else if (kb == 2) { areg = (u32x2){pkh(thz, thz), pkh(tmz, tmz)}; }
  else              { areg = (u32x2){pkh(1.f, 1.f), pkh(1.f, 0.f)}; }
  const f16x4 afrag = __builtin_bit_cast(f16x4, areg);
  const float Bv = -HKS * (tx * tx + ty * ty + tz * tz);

  __syncthreads();

  const float Amax = fmaxf(fmaxf(wmax[0], wmax[1]), fmaxf(wmax[2], wmax[3]));
  // C operand: per-lane constant Bp_q = B(row kb*4+q) - Amax
  const float Bp0 = __shfl(Bv, kb * 4 + 0) - Amax;
  const float Bp1 = __shfl(Bv, kb * 4 + 1) - Amax;
  const float Bp2 = __shfl(Bv, kb * 4 + 2) - Amax;
  const float Bp3 = __shfl(Bv, kb * 4 + 3) - Amax;
  const f32x4 cin = {Bp0, Bp1, Bp2, Bp3};

  // ---- tile loop: 64 tiles of 16 sources; ds_read_b64 per lane ----
  const u32x2* bptr = (const u32x2*)Bfr + (l15 * 4 + kb);
  float s0 = 0.f, s1 = 0.f, s2 = 0.f, s3 = 0.f;

  #pragma unroll 4
  for (int tile = 0; tile < HALF / 16; ++tile) {
    u32x2 braw = *bptr; bptr += 64;      // 16 sources x 4 u32x2 per tile
    f16x4 bfrag = __builtin_bit_cast(f16x4, braw);
    f32x4 d = mfma16x16x16(afrag, bfrag, cin);
    s0 += fexp2(d.x);
    s1 += fexp2(d.y);
    s2 += fexp2(d.z);
    s3 += fexp2(d.w);
  }

  // ---- reduce across the 16 col-lanes (same m̂ -> pure adds) ----
  #pragma unroll
  for (int off = 1; off <= 8; off <<= 1) {
    s0 += __shfl_xor(s0, off);
    s1 += __shfl_xor(s1, off);
    s2 += __shfl_xor(s2, off);
    s3 += __shfl_xor(s3, off);
  }

  // ---- store partials: m(row kb*4+q) = Amax - B_row = -Bp_q ----
  if (l15 == 0) {
    float* om = omA + (p * 2 + h) * NPTS;
    float* os = osA + (p * 2 + h) * NPTS;
    int r0 = rowbase + kb * 4;
    om[r0 + 0] = -Bp0; os[r0 + 0] = s0;
    om[r0 + 1] = -Bp1; os[r0 + 1] = s1;
    om[r0 + 2] = -Bp2; os[r0 + 2] = s2;
    om[r0 + 3] = -Bp3; os[r0 + 3] = s3;
  }
}

// ROUND-3-PROVEN parallel finalize: 96 WGs x 256 threads, deterministic
// double partials over the 98304 (side,problem,row) values.
__global__ void __launch_bounds__(256) sink_partial(
    const float* __restrict__ fm, const float* __restrict__ fs,
    const float* __restrict__ gm, const float* __restrict__ gs,
    const float* __restrict__ p1, const float* __restrict__ p2,
    double* __restrict__ part)
{
  __shared__ double wsum[4];
  const int tid = threadIdx.x;
  const int blk = blockIdx.x;
  const int PER_SIDE = NPROB * NPTS;     // 49152
  double acc = 0.0;
  #pragma unroll
  for (int k = 0; k < 4; ++k) {
    int idx = blk * 1024 + k * 256 + tid;
    int side = idx >= PER_SIDE;
    int rem  = idx - side * PER_SIDE;
    int p = rem >> 11;
    int i = rem & (NPTS - 1);
    const float* mA = side ? gm : fm;
    const float* sA = side ? gs : fs;
    float m0 = mA[(p * 2 + 0) * NPTS + i], m1 = mA[(p * 2 + 1) * NPTS + i];
    float c0 = sA[(p * 2 + 0) * NPTS + i], c1 = sA[(p * 2 + 1) * NPTS + i];
    float M = fmaxf(m0, m1);
    float S = fmaf(c0, fexp2(m0 - M), c1 * fexp2(m1 - M));
    int b = p / 3, kd = p - 3 * b;
    const float* rows = side ? (kd == 1 ? p1 : p2) : (kd == 2 ? p2 : p1);
    const float* pt = rows + b * (NPTS * 3) + 3 * i;
    float B = -HKS * (pt[0] * pt[0] + pt[1] * pt[1] + pt[2] * pt[2]);
    float val = NEG_EPS_LN2 * (M + B + flog2(fmaxf(S, 1e-38f)) - LOG2N);
    double wgt = (kd == 0) ? 1.0 : -0.5;
    acc += wgt * (double)val;
  }
  #pragma unroll
  for (int off = 1; off <= 32; off <<= 1) acc += __shfl_xor(acc, off);
  if ((tid & 63) == 0) wsum[tid >> 6] = acc;
  __syncthreads();
  if (tid == 0) part[blk] = ((wsum[0] + wsum[1]) + (wsum[2] + wsum[3]));
}

// Stage 2: one wave reduces the 96 partials.
__global__ void __launch_bounds__(64) sink_reduce(
    const double* __restrict__ part, float* __restrict__ out)
{
  const int tid = threadIdx.x;
  double acc = part[tid] + (tid < 32 ? part[64 + tid] : 0.0);
  #pragma unroll
  for (int off = 1; off <= 32; off <<= 1) acc += __shfl_xor(acc, off);
  if (tid == 0) out[0] = (float)(acc / (8.0 * 2048.0));
}

extern "C" void kernel_launch(void* const* d_in, const int* in_sizes, int n_in,
                              void* d_out, int out_size, void* d_ws, size_t ws_size,
                              hipStream_t stream)
{
  const float* p1 = (const float*)d_in[0];   // pcs1 [8,2048,3] f32
  const float* p2 = (const float*)d_in[1];   // pcs2 [8,2048,3] f32
  // workspace: 4 arrays of [24][2][2048] floats (m,s half-partials for f,g)
  // = 1.573 MB + 96 doubles — exact round-3-proven footprint.
  float* fm = (float*)d_ws;
  float* fs = fm + NPROB * 2 * NPTS;
  float* gm = fs + NPROB * 2 * NPTS;
  float* gs = gm + NPROB * 2 * NPTS;
  double* part = (double*)(gs + NPROB * 2 * NPTS);

  for (int t = 0; t < NPASS; ++t) {
    sink_mfma<<<dim3(NPROB * WGS_PER_PROB), dim3(THREADS), 0, stream>>>(
        p1, p2, fm, fs, gm, gs, t);
  }
  sink_partial<<<dim3(96), dim3(256), 0, stream>>>(fm, fs, gm, gs, p1, p2, part);
  sink_reduce<<<dim3(1), dim3(64), 0, stream>>>(part, (float*)d_out);
}

// Round 10
// 2001.388 us; speedup vs baseline: 1.2366x; 1.0240x over previous
//
#include <hip/hip_runtime.h>

#ifndef __has_builtin
#define __has_builtin(x) 0
#endif

__device__ __forceinline__ float fexp2(float x) {
#if __has_builtin(__builtin_amdgcn_exp2f)
  return __builtin_amdgcn_exp2f(x);   // v_exp_f32 (2^x)
#else
  return exp2f(x);
#endif
}
__device__ __forceinline__ float flog2(float x) {
#if __has_builtin(__builtin_amdgcn_logf)
  return __builtin_amdgcn_logf(x);    // v_log_f32 (log2)
#else
  return log2f(x);
#endif
}

typedef float    f32x4 __attribute__((ext_vector_type(4)));
typedef unsigned int u32x2 __attribute__((ext_vector_type(2)));
typedef unsigned int u32x4 __attribute__((ext_vector_type(4)));
typedef _Float16 f16x4 __attribute__((ext_vector_type(4)));

__device__ __forceinline__ f32x4 mfma16x16x16(f16x4 a, f16x4 b, f32x4 c) {
#if __has_builtin(__builtin_amdgcn_mfma_f32_16x16x16_f16)
  return __builtin_amdgcn_mfma_f32_16x16x16_f16(a, b, c, 0, 0, 0);
#else
  return __builtin_amdgcn_mfma_f32_16x16x16f16(a, b, c, 0, 0, 0);
#endif
}

namespace {
constexpr int NPTS = 2048;
constexpr int NPROB = 24;           // 8 batches x {xy, xx, yy}
constexpr int THREADS = 256;        // 4 waves x 16 rows each
constexpr int NPASS = 100;          // 50 Sinkhorn iters x 2 half-passes
constexpr float KS  = 1.44269504088896340736f / 0.0025f;   // log2(e)/eps
constexpr float HKS = 0.5f * KS;
constexpr float NEG_EPS_LN2 = -0.0025f * 0.69314718055994530942f; // -eps*ln2
constexpr float LOG2N = 11.0f;                             // log2(2048)
}

// 2-way f16 split: v ~= h + m, residual <= 2^-24|v| (dropped).
__device__ __forceinline__ void split2h(float v, float& h, float& m) {
  h = (float)(_Float16)v;
  m = (float)(_Float16)(v - h);
}
// 3-way f16 split: v == h + m + l EXACTLY (11+11+2 bits cover f32's 24).
__device__ __forceinline__ void split3h(float v, float& h, float& m, float& l) {
  h = (float)(_Float16)v;
  float r1 = v - h;
  m = (float)(_Float16)r1;
  l = r1 - m;
}
// pack two f32 as f16 into one VGPR: a -> k-even (low16), b -> k-odd.
__device__ __forceinline__ unsigned pkh(float a, float b) {
  unsigned short ab = __builtin_bit_cast(unsigned short, (_Float16)a);
  unsigned short bb = __builtin_bit_cast(unsigned short, (_Float16)b);
  return (unsigned)ab | ((unsigned)bb << 16);
}

// MFMA pass, NS-way source split (NS=4 preferred: LDS 16.4KB -> 8 WG/CU =
// 8 waves/SIMD so the v_exp trans pipe (16 cyc/wave-instr, the 10.2 us/pass
// floor) stays fed; NS=2 is the round-9-proven fallback if ws_size is small).
// WG (p, blk, h): 64 target rows (4 waves x 16), partial LSE over sources
// j in [SRC*h, SRC*h+SRC), SRC = 2048/NS.
//   exp-arg(r,j) = t_r.(KS*s_j) + A_j + B_r - Amax   (<= 0 a-priori + ~2e-4 slop)
//   A_j = KS*phi_j - HKS|s_j|^2, B_r = -HKS|t_r|^2, Amax = max_j(KS*phi_j).
// KS on the SOURCE side only (round-8 fix). mfma_f32_16x16x16_f16, 15 slots:
//   kb0 x: th*sh, th*sm, tm*sh, tm*sm   kb1 y, kb2 z: same
//   kb3: 1*Ah, 1*Am, 1*Al, 0 (A exact 3-way)
// Dropped l-terms <= ~7e-5/coord log2-units (round-9 passed absmax 0.0).
// B-frag 32B/source; ds_read_b64/lane/tile = exactly the unique data.
// Layouts (gfx950): A row=l&15; B col=l&15; shared k-map (pairing
// permutation-immune); D col=l&15 row=4*(l>>4)+reg [m89].
// Stored partials: contract LSE_part - B_r = m + log2(s), m = Amax - B_r.
template <int NS>
__global__ void __launch_bounds__(THREADS, 8) sink_mfma(
    const float* __restrict__ p1, const float* __restrict__ p2,
    float* __restrict__ fm, float* __restrict__ fs,
    float* __restrict__ gm, float* __restrict__ gs, int t)
{
  constexpr int SRC = NPTS / NS;
  extern __shared__ char smem[];
  u32x4* Bfr  = (u32x4*)smem;                 // SRC*2 entries (32B/source)
  float* wmax = (float*)(smem + SRC * 32);    // 4 floats

  const int w   = blockIdx.x;
  const int p   = w / (32 * NS);    // problem 0..23
  const int r_  = w - p * (32 * NS);
  const int blk = r_ & 31;          // row-block (64 rows)
  const int h   = r_ >> 5;          // source slice 0..NS-1
  const int b    = p / 3;
  const int kind = p - 3 * b;       // 0: xy, 1: xx, 2: yy
  const float* X = (kind == 2 ? p2 : p1) + b * (NPTS * 3);
  const float* Y = (kind == 1 ? p1 : p2) + b * (NPTS * 3);

  const bool even = (t & 1) == 0;
  const float* tgt = even ? X : Y;
  const float* src = even ? Y : X;
  const float* pmA = even ? gm : fm;
  const float* psA = even ? gs : fs;
  float* omA = even ? fm : gm;
  float* osA = even ? fs : gs;

  const int tid  = threadIdx.x;
  const int lane = tid & 63;
  const int wv   = tid >> 6;        // wave 0..3
  const int l15  = lane & 15;
  const int kb   = lane >> 4;       // k-block this lane supplies

  // ---- stage sources: merge prev NS partials -> A_j; build B-frags ----
  float am = -1e30f;
  #pragma unroll
  for (int i = 0; i < SRC / THREADS; ++i) {
    int jl = tid + THREADS * i;
    int jg = SRC * h + jl;
    float sx = src[3 * jg + 0], sy = src[3 * jg + 1], sz = src[3 * jg + 2];
    float q2 = HKS * (sx * sx + sy * sy + sz * sz);
    float A;
    if (t == 0) {
      A = -q2;
    } else {
      float M = pmA[(p * NS + 0) * NPTS + jg];
      #pragma unroll
      for (int q = 1; q < NS; ++q)
        M = fmaxf(M, pmA[(p * NS + q) * NPTS + jg]);
      float S = 0.f;
      #pragma unroll
      for (int q = 0; q < NS; ++q)
        S = fmaf(psA[(p * NS + q) * NPTS + jg],
                 fexp2(pmA[(p * NS + q) * NPTS + jg] - M), S);
      A = LOG2N - M - flog2(fmaxf(S, 1e-38f));   // = KS*phi_j - HKS|s_j|^2
    }
    am = fmaxf(am, A + q2);          // = KS*phi_j (t==0: exactly 0)
    float shx, smx, shy, smy, shz, smz, Ah, Am, Al;
    split2h(KS * sx, shx, smx);      // SOURCE carries the KS scale
    split2h(KS * sy, shy, smy);
    split2h(KS * sz, shz, smz);
    split3h(A, Ah, Am, Al);          // exact: A == Ah+Am+Al
    unsigned wx = pkh(shx, smx), wy = pkh(shy, smy), wz = pkh(shz, smz);
    Bfr[jl * 2 + 0] = (u32x4){wx, wx, wy, wy};                    // kb0 | kb1
    Bfr[jl * 2 + 1] = (u32x4){wz, wz, pkh(Ah, Am), pkh(Al, 0.f)}; // kb2 | kb3
  }

  #pragma unroll
  for (int off = 1; off <= 32; off <<= 1) am = fmaxf(am, __shfl_xor(am, off));
  if (lane == 0) wmax[wv] = am;

  // ---- per-lane A-frag: RAW target coords, 2-way split ----
  const int rowbase = blk * 64 + wv * 16;
  const int r = rowbase + l15;
  float tx = tgt[3 * r + 0], ty = tgt[3 * r + 1], tz = tgt[3 * r + 2];
  float thx, tmx, thy, tmy, thz, tmz;
  split2h(tx, thx, tmx);
  split2h(ty, thy, tmy);
  split2h(tz, thz, tmz);
  u32x2 areg;
  if (kb == 0)      { areg = (u32x2){pkh(thx, thx), pkh(tmx, tmx)}; }
  else if (kb == 1) { areg = (u32x2){pkh(thy, thy), pkh(tmy, tmy)}; }
  else if (kb == 2) { areg = (u32x2){pkh(thz, thz), pkh(tmz, tmz)}; }
  else              { areg = (u32x2){pkh(1.f, 1.f), pkh(1.f, 0.f)}; }
  const f16x4 afrag = __builtin_bit_cast(f16x4, areg);
  const float Bv = -HKS * (tx * tx + ty * ty + tz * tz);

  __syncthreads();

  const float Amax = fmaxf(fmaxf(wmax[0], wmax[1]), fmaxf(wmax[2], wmax[3]));
  // C operand: per-lane constant Bp_q = B(row kb*4+q) - Amax
  const float Bp0 = __shfl(Bv, kb * 4 + 0) - Amax;
  const float Bp1 = __shfl(Bv, kb * 4 + 1) - Amax;
  const float Bp2 = __shfl(Bv, kb * 4 + 2) - Amax;
  const float Bp3 = __shfl(Bv, kb * 4 + 3) - Amax;
  const f32x4 cin = {Bp0, Bp1, Bp2, Bp3};

  // ---- tile loop: SRC/16 tiles of 16 sources; ds_read_b64 per lane ----
  const u32x2* bptr = (const u32x2*)Bfr + (l15 * 4 + kb);
  float s0 = 0.f, s1 = 0.f, s2 = 0.f, s3 = 0.f;

  #pragma unroll 4
  for (int tile = 0; tile < SRC / 16; ++tile) {
    u32x2 braw = *bptr; bptr += 64;      // 16 sources x 4 u32x2 per tile
    f16x4 bfrag = __builtin_bit_cast(f16x4, braw);
    f32x4 d = mfma16x16x16(afrag, bfrag, cin);
    s0 += fexp2(d.x);
    s1 += fexp2(d.y);
    s2 += fexp2(d.z);
    s3 += fexp2(d.w);
  }

  // ---- reduce across the 16 col-lanes (same m̂ -> pure adds) ----
  #pragma unroll
  for (int off = 1; off <= 8; off <<= 1) {
    s0 += __shfl_xor(s0, off);
    s1 += __shfl_xor(s1, off);
    s2 += __shfl_xor(s2, off);
    s3 += __shfl_xor(s3, off);
  }

  // ---- store partials: m(row kb*4+q) = Amax - B_row = -Bp_q ----
  if (l15 == 0) {
    float* om = omA + (p * NS + h) * NPTS;
    float* os = osA + (p * NS + h) * NPTS;
    int r0 = rowbase + kb * 4;
    om[r0 + 0] = -Bp0; os[r0 + 0] = s0;
    om[r0 + 1] = -Bp1; os[r0 + 1] = s1;
    om[r0 + 2] = -Bp2; os[r0 + 2] = s2;
    om[r0 + 3] = -Bp3; os[r0 + 3] = s3;
  }
}

// Parallel finalize (round-3/9-proven structure, NS runtime): 96 WGs x 256,
// deterministic double partials over the 98304 (side,problem,row) values.
__global__ void __launch_bounds__(256) sink_partial(
    const float* __restrict__ fm, const float* __restrict__ fs,
    const float* __restrict__ gm, const float* __restrict__ gs,
    const float* __restrict__ p1, const float* __restrict__ p2,
    double* __restrict__ part, int ns)
{
  __shared__ double wsum[4];
  const int tid = threadIdx.x;
  const int blk = blockIdx.x;
  const int PER_SIDE = NPROB * NPTS;     // 49152
  double acc = 0.0;
  #pragma unroll
  for (int k = 0; k < 4; ++k) {
    int idx = blk * 1024 + k * 256 + tid;
    int side = idx >= PER_SIDE;
    int rem  = idx - side * PER_SIDE;
    int p = rem >> 11;
    int i = rem & (NPTS - 1);
    const float* mA = side ? gm : fm;
    const float* sA = side ? gs : fs;
    float M = mA[(p * ns + 0) * NPTS + i];
    for (int q = 1; q < ns; ++q) M = fmaxf(M, mA[(p * ns + q) * NPTS + i]);
    float S = 0.f;
    for (int q = 0; q < ns; ++q)
      S = fmaf(sA[(p * ns + q) * NPTS + i],
               fexp2(mA[(p * ns + q) * NPTS + i] - M), S);
    int b = p / 3, kd = p - 3 * b;
    const float* rows = side ? (kd == 1 ? p1 : p2) : (kd == 2 ? p2 : p1);
    const float* pt = rows + b * (NPTS * 3) + 3 * i;
    float B = -HKS * (pt[0] * pt[0] + pt[1] * pt[1] + pt[2] * pt[2]);
    float val = NEG_EPS_LN2 * (M + B + flog2(fmaxf(S, 1e-38f)) - LOG2N);
    double wgt = (kd == 0) ? 1.0 : -0.5;
    acc += wgt * (double)val;
  }
  #pragma unroll
  for (int off = 1; off <= 32; off <<= 1) acc += __shfl_xor(acc, off);
  if ((tid & 63) == 0) wsum[tid >> 6] = acc;
  __syncthreads();
  if (tid == 0) part[blk] = ((wsum[0] + wsum[1]) + (wsum[2] + wsum[3]));
}

// Stage 2: one wave reduces the 96 partials.
__global__ void __launch_bounds__(64) sink_reduce(
    const double* __restrict__ part, float* __restrict__ out)
{
  const int tid = threadIdx.x;
  double acc = part[tid] + (tid < 32 ? part[64 + tid] : 0.0);
  #pragma unroll
  for (int off = 1; off <= 32; off <<= 1) acc += __shfl_xor(acc, off);
  if (tid == 0) out[0] = (float)(acc / (8.0 * 2048.0));
}

extern "C" void kernel_launch(void* const* d_in, const int* in_sizes, int n_in,
                              void* d_out, int out_size, void* d_ws, size_t ws_size,
                              hipStream_t stream)
{
  const float* p1 = (const float*)d_in[0];   // pcs1 [8,2048,3] f32
  const float* p2 = (const float*)d_in[1];   // pcs2 [8,2048,3] f32

  // Preferred NS=4 (3.15 MB partials); fall back to proven NS=2 (1.57 MB)
  // if the workspace is small. part array sits after the 4 partial arrays.
  const size_t elems4 = (size_t)NPROB * 4 * NPTS;   // per array, NS=4
  const size_t need4  = 4 * elems4 * sizeof(float) + 96 * sizeof(double);
  const int ns = (ws_size >= need4) ? 4 : 2;
  const size_t elems = (size_t)NPROB * ns * NPTS;

  float* fm = (float*)d_ws;
  float* fs = fm + elems;
  float* gm = fs + elems;
  float* gs = gm + elems;
  double* part = (double*)(gs + elems);

  const int grid = NPROB * 32 * ns;
  const int shmem = (NPTS / ns) * 32 + 16;   // Bfr + wmax

  for (int t = 0; t < NPASS; ++t) {
    if (ns == 4)
      sink_mfma<4><<<dim3(grid), dim3(THREADS), shmem, stream>>>(
          p1, p2, fm, fs, gm, gs, t);
    else
      sink_mfma<2><<<dim3(grid), dim3(THREADS), shmem, stream>>>(
          p1, p2, fm, fs, gm, gs, t);
  }
  sink_partial<<<dim3(96), dim3(256), 0, stream>>>(fm, fs, gm, gs, p1, p2,
                                                   part, ns);
  sink_reduce<<<dim3(1), dim3(64), 0, stream>>>(part, (float*)d_out);
}

// Round 11
// 1915.976 us; speedup vs baseline: 1.2917x; 1.0446x over previous
//
#include <hip/hip_runtime.h>

#ifndef __has_builtin
#define __has_builtin(x) 0
#endif

__device__ __forceinline__ float fexp2(float x) {
#if __has_builtin(__builtin_amdgcn_exp2f)
  return __builtin_amdgcn_exp2f(x);   // v_exp_f32 (2^x)
#else
  return exp2f(x);
#endif
}
__device__ __forceinline__ float flog2(float x) {
#if __has_builtin(__builtin_amdgcn_logf)
  return __builtin_amdgcn_logf(x);    // v_log_f32 (log2)
#else
  return log2f(x);
#endif
}

typedef float    f32x4 __attribute__((ext_vector_type(4)));
typedef unsigned int u32x2 __attribute__((ext_vector_type(2)));
typedef unsigned int u32x4 __attribute__((ext_vector_type(4)));
typedef _Float16 f16x4 __attribute__((ext_vector_type(4)));

__device__ __forceinline__ f32x4 mfma16x16x16(f16x4 a, f16x4 b, f32x4 c) {
#if __has_builtin(__builtin_amdgcn_mfma_f32_16x16x16_f16)
  return __builtin_amdgcn_mfma_f32_16x16x16_f16(a, b, c, 0, 0, 0);
#else
  return __builtin_amdgcn_mfma_f32_16x16x16f16(a, b, c, 0, 0, 0);
#endif
}

namespace {
constexpr int NPTS = 2048;
constexpr int NPROB = 24;           // 8 batches x {xy, xx, yy}
constexpr int THREADS = 256;        // 4 waves x 16 rows each
constexpr int NPASS = 100;          // 50 Sinkhorn iters x 2 half-passes
constexpr int PH = 512;             // sources staged per phase (2 phases/WG)
constexpr float KS  = 1.44269504088896340736f / 0.0025f;   // log2(e)/eps
constexpr float HKS = 0.5f * KS;
constexpr float NEG_EPS_LN2 = -0.0025f * 0.69314718055994530942f; // -eps*ln2
constexpr float LOG2N = 11.0f;                             // log2(2048)
}

// 2-way f16 split: v ~= h + m, residual <= 2^-24|v| (dropped).
__device__ __forceinline__ void split2h(float v, float& h, float& m) {
  h = (float)(_Float16)v;
  m = (float)(_Float16)(v - h);
}
// 3-way f16 split: v == h + m + l EXACTLY (11+11+2 bits cover f32's 24).
__device__ __forceinline__ void split3h(float v, float& h, float& m, float& l) {
  h = (float)(_Float16)v;
  float r1 = v - h;
  m = (float)(_Float16)r1;
  l = r1 - m;
}
// pack two f32 as f16 into one VGPR: a -> k-even (low16), b -> k-odd.
__device__ __forceinline__ unsigned pkh(float a, float b) {
  unsigned short ab = __builtin_bit_cast(unsigned short, (_Float16)a);
  unsigned short bb = __builtin_bit_cast(unsigned short, (_Float16)b);
  return (unsigned)ab | ((unsigned)bb << 16);
}

// MFMA pass, single-generation geometry (round-11):
//   grid 1536 (= 24 probs x 32 row-blocks x 2 source-halves) with LDS cut to
//   16.4 KB by staging the WG's 1024 sources in TWO sequential 512-phases
//   (one reused buffer). Capacity = min(LDS 9, wave-cap 8) = 8 WG/CU >= the
//   6 WG/CU the grid asks for -> ALL WGs resident from dispatch, zero tail
//   generations, uniform 6 waves/SIMD. Rounds 9/10 both ran 1.5-generation
//   schedules (cap 4 vs need 6; cap 8 vs need 12) -> identical ~20-30% tail
//   loss, which is why doubling occupancy was null (round-10 lesson).
// Math (round-8/9-proven): exp-arg(r,j) = t_r.(KS*s_j) + A_j + B_r - Amax_ph,
//   A_j = KS*phi_j - HKS|s_j|^2, B_r = -HKS|t_r|^2, Amax_ph = max KS*phi over
//   the phase's 512 sources. mfma_f32_16x16x16_f16, 15 slots: kb0/1/2 =
//   x/y/z {th*sh, th*sm, tm*sh, tm*sm} (t raw 2-way, s KS-scaled 2-way),
//   kb3 = 1*{Ah,Am,Al} (A exact 3-way). Phase merge: m_ph = Amax_ph - B_r
//   differs only by the wave-uniform Amax_ph -> s = s0*f0 + s1*f1 with
//   f_h = 2^(Amax_h - max(Amax)), 2 exps total.
// Stored partials (NS=2 contract, proven ws layout): m = max(Amax) - B_r, s.
__global__ void __launch_bounds__(THREADS, 8) sink_mfma(
    const float* __restrict__ p1, const float* __restrict__ p2,
    float* __restrict__ fm, float* __restrict__ fs,
    float* __restrict__ gm, float* __restrict__ gs, int t)
{
  __shared__ u32x4 Bfr[PH * 2];     // 16384 B: one 512-source frag buffer
  __shared__ float wmax[4];

  const int w   = blockIdx.x;
  const int p   = w >> 6;           // problem 0..23
  const int r_  = w & 63;
  const int blk = r_ & 31;          // row-block (64 rows)
  const int h   = r_ >> 5;          // source half 0/1
  const int b    = p / 3;
  const int kind = p - 3 * b;       // 0: xy, 1: xx, 2: yy
  const float* X = (kind == 2 ? p2 : p1) + b * (NPTS * 3);
  const float* Y = (kind == 1 ? p1 : p2) + b * (NPTS * 3);

  const bool even = (t & 1) == 0;
  const float* tgt = even ? X : Y;
  const float* src = even ? Y : X;
  const float* pmA = even ? gm : fm;
  const float* psA = even ? gs : fs;
  float* omA = even ? fm : gm;
  float* osA = even ? fs : gs;

  const int tid  = threadIdx.x;
  const int lane = tid & 63;
  const int wv   = tid >> 6;        // wave 0..3
  const int l15  = lane & 15;
  const int kb   = lane >> 4;       // k-block this lane supplies

  // ---- per-lane A-frag: RAW target coords, 2-way split (once) ----
  const int rowbase = blk * 64 + wv * 16;
  {
  }
  const int r = rowbase + l15;
  float tx = tgt[3 * r + 0], ty = tgt[3 * r + 1], tz = tgt[3 * r + 2];
  float thx, tmx, thy, tmy, thz, tmz;
  split2h(tx, thx, tmx);
  split2h(ty, thy, tmy);
  split2h(tz, thz, tmz);
  u32x2 areg;
  if (kb == 0)      { areg = (u32x2){pkh(thx, thx), pkh(tmx, tmx)}; }
  else if (kb == 1) { areg = (u32x2){pkh(thy, thy), pkh(tmy, tmy)}; }
  else if (kb == 2) { areg = (u32x2){pkh(thz, thz), pkh(tmz, tmz)}; }
  else              { areg = (u32x2){pkh(1.f, 1.f), pkh(1.f, 0.f)}; }
  const f16x4 afrag = __builtin_bit_cast(f16x4, areg);
  const float Bv = -HKS * (tx * tx + ty * ty + tz * tz);
  // this lane's 4 output rows' B values (wave-lane constant)
  const float Bq0 = __shfl(Bv, kb * 4 + 0);
  const float Bq1 = __shfl(Bv, kb * 4 + 1);
  const float Bq2 = __shfl(Bv, kb * 4 + 2);
  const float Bq3 = __shfl(Bv, kb * 4 + 3);

  float Amax0 = 0.f, Amax1 = 0.f;
  float sA0, sA1, sA2, sA3;         // phase-0 reduced row sums
  float sB0, sB1, sB2, sB3;         // phase-1

  #pragma unroll
  for (int h2 = 0; h2 < 2; ++h2) {
    // ---- stage 512 sources of this phase ----
    float am = -1e30f;
    #pragma unroll
    for (int i = 0; i < PH / THREADS; ++i) {
      int jl = tid + THREADS * i;
      int jg = 1024 * h + PH * h2 + jl;
      float sx = src[3 * jg + 0], sy = src[3 * jg + 1], sz = src[3 * jg + 2];
      float q2 = HKS * (sx * sx + sy * sy + sz * sz);
      float A;
      if (t == 0) {
        A = -q2;
      } else {
        float m0 = pmA[(p * 2 + 0) * NPTS + jg];
        float m1 = pmA[(p * 2 + 1) * NPTS + jg];
        float c0 = psA[(p * 2 + 0) * NPTS + jg];
        float c1 = psA[(p * 2 + 1) * NPTS + jg];
        float M = fmaxf(m0, m1);
        float S = fmaf(c0, fexp2(m0 - M), c1 * fexp2(m1 - M));
        A = LOG2N - M - flog2(fmaxf(S, 1e-38f));   // = KS*phi_j - HKS|s_j|^2
      }
      am = fmaxf(am, A + q2);        // = KS*phi_j (t==0: exactly 0)
      float shx, smx, shy, smy, shz, smz, Ah, Am, Al;
      split2h(KS * sx, shx, smx);    // SOURCE carries the KS scale
      split2h(KS * sy, shy, smy);
      split2h(KS * sz, shz, smz);
      split3h(A, Ah, Am, Al);        // exact: A == Ah+Am+Al
      unsigned wx = pkh(shx, smx), wy = pkh(shy, smy), wz = pkh(shz, smz);
      Bfr[jl * 2 + 0] = (u32x4){wx, wx, wy, wy};                    // kb0|kb1
      Bfr[jl * 2 + 1] = (u32x4){wz, wz, pkh(Ah, Am), pkh(Al, 0.f)}; // kb2|kb3
    }
    #pragma unroll
    for (int off = 1; off <= 32; off <<= 1) am = fmaxf(am, __shfl_xor(am, off));
    if (lane == 0) wmax[wv] = am;
    __syncthreads();

    const float Amax = fmaxf(fmaxf(wmax[0], wmax[1]), fmaxf(wmax[2], wmax[3]));
    const f32x4 cin = {Bq0 - Amax, Bq1 - Amax, Bq2 - Amax, Bq3 - Amax};

    // ---- tile loop: 32 tiles of 16 sources; ds_read_b64 per lane ----
    const u32x2* bptr = (const u32x2*)Bfr + (l15 * 4 + kb);
    float s0 = 0.f, s1 = 0.f, s2 = 0.f, s3 = 0.f;
    #pragma unroll 4
    for (int tile = 0; tile < PH / 16; ++tile) {
      u32x2 braw = *bptr; bptr += 64;    // 16 sources x 4 u32x2 per tile
      f16x4 bfrag = __builtin_bit_cast(f16x4, braw);
      f32x4 d = mfma16x16x16(afrag, bfrag, cin);
      s0 += fexp2(d.x);
      s1 += fexp2(d.y);
      s2 += fexp2(d.z);
      s3 += fexp2(d.w);
    }

    // ---- reduce across the 16 col-lanes (same m̂ -> pure adds) ----
    #pragma unroll
    for (int off = 1; off <= 8; off <<= 1) {
      s0 += __shfl_xor(s0, off);
      s1 += __shfl_xor(s1, off);
      s2 += __shfl_xor(s2, off);
      s3 += __shfl_xor(s3, off);
    }

    if (h2 == 0) { Amax0 = Amax; sA0 = s0; sA1 = s1; sA2 = s2; sA3 = s3; }
    else         { Amax1 = Amax; sB0 = s0; sB1 = s1; sB2 = s2; sB3 = s3; }
    __syncthreads();   // Bfr/wmax safe to overwrite next phase
  }

  // ---- merge phases: Amax diff is wave-uniform -> 2 exps total ----
  const float Mx = fmaxf(Amax0, Amax1);
  const float f0 = fexp2(Amax0 - Mx);
  const float f1 = fexp2(Amax1 - Mx);
  const float s0 = fmaf(sA0, f0, sB0 * f1);
  const float s1 = fmaf(sA1, f0, sB1 * f1);
  const float s2 = fmaf(sA2, f0, sB2 * f1);
  const float s3 = fmaf(sA3, f0, sB3 * f1);

  // ---- store partials: m(row kb*4+q) = Mx - B_q ----
  if (l15 == 0) {
    float* om = omA + (p * 2 + h) * NPTS;
    float* os = osA + (p * 2 + h) * NPTS;
    int r0 = rowbase + kb * 4;
    om[r0 + 0] = Mx - Bq0; os[r0 + 0] = s0;
    om[r0 + 1] = Mx - Bq1; os[r0 + 1] = s1;
    om[r0 + 2] = Mx - Bq2; os[r0 + 2] = s2;
    om[r0 + 3] = Mx - Bq3; os[r0 + 3] = s3;
  }
}

// Parallel finalize (round-9-proven, ns=2): 96 WGs x 256, deterministic
// double partials over the 98304 (side,problem,row) values.
__global__ void __launch_bounds__(256) sink_partial(
    const float* __restrict__ fm, const float* __restrict__ fs,
    const float* __restrict__ gm, const float* __restrict__ gs,
    const float* __restrict__ p1, const float* __restrict__ p2,
    double* __restrict__ part)
{
  __shared__ double wsum[4];
  const int tid = threadIdx.x;
  const int blk = blockIdx.x;
  const int PER_SIDE = NPROB * NPTS;     // 49152
  double acc = 0.0;
  #pragma unroll
  for (int k = 0; k < 4; ++k) {
    int idx = blk * 1024 + k * 256 + tid;
    int side = idx >= PER_SIDE;
    int rem  = idx - side * PER_SIDE;
    int p = rem >> 11;
    int i = rem & (NPTS - 1);
    const float* mA = side ? gm : fm;
    const float* sA = side ? gs : fs;
    float m0 = mA[(p * 2 + 0) * NPTS + i], m1 = mA[(p * 2 + 1) * NPTS + i];
    float c0 = sA[(p * 2 + 0) * NPTS + i], c1 = sA[(p * 2 + 1) * NPTS + i];
    float M = fmaxf(m0, m1);
    float S = fmaf(c0, fexp2(m0 - M), c1 * fexp2(m1 - M));
    int b = p / 3, kd = p - 3 * b;
    const float* rows = side ? (kd == 1 ? p1 : p2) : (kd == 2 ? p2 : p1);
    const float* pt = rows + b * (NPTS * 3) + 3 * i;
    float B = -HKS * (pt[0] * pt[0] + pt[1] * pt[1] + pt[2] * pt[2]);
    float val = NEG_EPS_LN2 * (M + B + flog2(fmaxf(S, 1e-38f)) - LOG2N);
    double wgt = (kd == 0) ? 1.0 : -0.5;
    acc += wgt * (double)val;
  }
  #pragma unroll
  for (int off = 1; off <= 32; off <<= 1) acc += __shfl_xor(acc, off);
  if ((tid & 63) == 0) wsum[tid >> 6] = acc;
  __syncthreads();
  if (tid == 0) part[blk] = ((wsum[0] + wsum[1]) + (wsum[2] + wsum[3]));
}

// Stage 2: one wave reduces the 96 partials.
__global__ void __launch_bounds__(64) sink_reduce(
    const double* __restrict__ part, float* __restrict__ out)
{
  const int tid = threadIdx.x;
  double acc = part[tid] + (tid < 32 ? part[64 + tid] : 0.0);
  #pragma unroll
  for (int off = 1; off <= 32; off <<= 1) acc += __shfl_xor(acc, off);
  if (tid == 0) out[0] = (float)(acc / (8.0 * 2048.0));
}

extern "C" void kernel_launch(void* const* d_in, const int* in_sizes, int n_in,
                              void* d_out, int out_size, void* d_ws, size_t ws_size,
                              hipStream_t stream)
{
  const float* p1 = (const float*)d_in[0];   // pcs1 [8,2048,3] f32
  const float* p2 = (const float*)d_in[1];   // pcs2 [8,2048,3] f32
  // workspace: 4 arrays of [24][2][2048] floats (m,s half-partials for f,g)
  // = 1.573 MB + 96 doubles — proven NS=2 footprint (no ws_size gamble).
  const size_t elems = (size_t)NPROB * 2 * NPTS;
  float* fm = (float*)d_ws;
  float* fs = fm + elems;
  float* gm = fs + elems;
  float* gs = gm + elems;
  double* part = (double*)(gs + elems);

  for (int t = 0; t < NPASS; ++t) {
    sink_mfma<<<dim3(NPROB * 64), dim3(THREADS), 0, stream>>>(
        p1, p2, fm, fs, gm, gs, t);
  }
  sink_partial<<<dim3(96), dim3(256), 0, stream>>>(fm, fs, gm, gs, p1, p2, part);
  sink_reduce<<<dim3(1), dim3(64), 0, stream>>>(part, (float*)d_out);
}

// Round 12
// 1890.030 us; speedup vs baseline: 1.3095x; 1.0137x over previous
//
#include <hip/hip_runtime.h>

#ifndef __has_builtin
#define __has_builtin(x) 0
#endif

__device__ __forceinline__ float fexp2(float x) {
#if __has_builtin(__builtin_amdgcn_exp2f)
  return __builtin_amdgcn_exp2f(x);   // v_exp_f32 (2^x)
#else
  return exp2f(x);
#endif
}
__device__ __forceinline__ float flog2(float x) {
#if __has_builtin(__builtin_amdgcn_logf)
  return __builtin_amdgcn_logf(x);    // v_log_f32 (log2)
#else
  return log2f(x);
#endif
}

typedef float    f32x4 __attribute__((ext_vector_type(4)));
typedef unsigned int u32x2 __attribute__((ext_vector_type(2)));
typedef unsigned int u32x4 __attribute__((ext_vector_type(4)));
typedef _Float16 f16x4 __attribute__((ext_vector_type(4)));

__device__ __forceinline__ f32x4 mfma16x16x16(f16x4 a, f16x4 b, f32x4 c) {
#if __has_builtin(__builtin_amdgcn_mfma_f32_16x16x16_f16)
  return __builtin_amdgcn_mfma_f32_16x16x16_f16(a, b, c, 0, 0, 0);
#else
  return __builtin_amdgcn_mfma_f32_16x16x16f16(a, b, c, 0, 0, 0);
#endif
}

namespace {
constexpr int NPTS = 2048;
constexpr int NPROB = 24;           // 8 batches x {xy, xx, yy}
constexpr int THREADS = 256;        // 4 waves x 16 rows each
constexpr int NPASS = 100;          // 50 Sinkhorn iters x 2 half-passes
constexpr int PH = 512;             // sources staged per phase (2 phases/WG)
constexpr float KS  = 1.44269504088896340736f / 0.0025f;   // log2(e)/eps
constexpr float HKS = 0.5f * KS;
constexpr float NEG_EPS_LN2 = -0.0025f * 0.69314718055994530942f; // -eps*ln2
constexpr float LOG2N = 11.0f;                             // log2(2048)
}

// 2-way f16 split: v ~= h + m, residual <= 2^-24|v| (dropped).
__device__ __forceinline__ void split2h(float v, float& h, float& m) {
  h = (float)(_Float16)v;
  m = (float)(_Float16)(v - h);
}
// 3-way f16 split: v == h + m + l EXACTLY (11+11+2 bits cover f32's 24).
__device__ __forceinline__ void split3h(float v, float& h, float& m, float& l) {
  h = (float)(_Float16)v;
  float r1 = v - h;
  m = (float)(_Float16)r1;
  l = r1 - m;
}
// pack two f32 as f16 into one VGPR: a -> k-even (low16), b -> k-odd.
__device__ __forceinline__ unsigned pkh(float a, float b) {
  unsigned short ab = __builtin_bit_cast(unsigned short, (_Float16)a);
  unsigned short bb = __builtin_bit_cast(unsigned short, (_Float16)b);
  return (unsigned)ab | ((unsigned)bb << 16);
}

// One-time prep: per (batch,cloud) point set (16 sets of 2048), precompute the
// pass-invariant source data: packed f16 splits of KS*s (wx,wy,wz) and
// q2 = HKS|s|^2, as one u32x4/source. Hoists ~60% of the per-pass staging
// VALU (3x split2h + 3x pkh + q2) out of the 100-pass loop (round-12 change).
__global__ void __launch_bounds__(256) sink_prep(
    const float* __restrict__ p1, const float* __restrict__ p2,
    u32x4* __restrict__ pre)
{
  const int g = blockIdx.x;          // 0..127
  const int set = g >> 3;            // 0..15: 0-7 = p1 batches, 8-15 = p2
  const int j = (g & 7) * 256 + threadIdx.x;
  const float* src = (set < 8) ? p1 + set * (NPTS * 3)
                               : p2 + (set - 8) * (NPTS * 3);
  float sx = src[3 * j + 0], sy = src[3 * j + 1], sz = src[3 * j + 2];
  float q2 = HKS * (sx * sx + sy * sy + sz * sz);
  float shx, smx, shy, smy, shz, smz;
  split2h(KS * sx, shx, smx);
  split2h(KS * sy, shy, smy);
  split2h(KS * sz, shz, smz);
  pre[set * NPTS + j] =
      (u32x4){pkh(shx, smx), pkh(shy, smy), pkh(shz, smz), __float_as_uint(q2)};
}

// MFMA pass (single-generation geometry, round-11-proven): grid 1536, LDS
// 16.4 KB (two sequential 512-source phases, one reused buffer) -> 6 WG/CU
// all resident from dispatch. Round-12: PRE path loads the precomputed
// u32x4/source (1 dwordx4) instead of raw floats + splits; staging computes
// only the A-dependent part. Phases merge on-the-fly (running Mx,s) to cut
// cross-phase register state (~10 -> ~5) under the 64-VGPR cap (8 waves/EU).
// Math (round-8/9-proven): exp-arg(r,j) = t_r.(KS*s_j) + A_j + B_r - Amax_ph,
//   A_j = KS*phi_j - HKS|s_j|^2, B_r = -HKS|t_r|^2. mfma_f32_16x16x16_f16,
//   15 slots: kb0/1/2 = x/y/z {th*sh,th*sm,tm*sh,tm*sm}, kb3 = 1*{Ah,Am,Al}.
// Stored partials (NS=2 contract): m = Mx - B_r, s;  LSE_part = m + log2 s + B_r.
template <bool PRE>
__global__ void __launch_bounds__(THREADS, 8) sink_mfma(
    const float* __restrict__ p1, const float* __restrict__ p2,
    float* __restrict__ fm, float* __restrict__ fs,
    float* __restrict__ gm, float* __restrict__ gs,
    const u32x4* __restrict__ pre, int t)
{
  __shared__ u32x4 Bfr[PH * 2];     // 16384 B: one 512-source frag buffer
  __shared__ float wmax[4];

  const int w   = blockIdx.x;
  const int p   = w >> 6;           // problem 0..23
  const int r_  = w & 63;
  const int blk = r_ & 31;          // row-block (64 rows)
  const int h   = r_ >> 5;          // source half 0/1
  const int b    = p / 3;
  const int kind = p - 3 * b;       // 0: xy, 1: xx, 2: yy
  const float* X = (kind == 2 ? p2 : p1) + b * (NPTS * 3);
  const float* Y = (kind == 1 ? p1 : p2) + b * (NPTS * 3);

  const bool even = (t & 1) == 0;
  const float* tgt = even ? X : Y;
  const float* src = even ? Y : X;
  // precomputed set id of the source cloud this pass
  const int sset = even ? (kind == 1 ? b : 8 + b) : (kind == 2 ? 8 + b : b);
  const u32x4* ps = pre + sset * NPTS;
  const float* pmA = even ? gm : fm;
  const float* psA = even ? gs : fs;
  float* omA = even ? fm : gm;
  float* osA = even ? fs : gs;

  const int tid  = threadIdx.x;
  const int lane = tid & 63;
  const int wv   = tid >> 6;        // wave 0..3
  const int l15  = lane & 15;
  const int kb   = lane >> 4;       // k-block this lane supplies

  // ---- per-lane A-frag: RAW target coords, 2-way split (once) ----
  const int rowbase = blk * 64 + wv * 16;
  const int r = rowbase + l15;
  float tx = tgt[3 * r + 0], ty = tgt[3 * r + 1], tz = tgt[3 * r + 2];
  float thx, tmx, thy, tmy, thz, tmz;
  split2h(tx, thx, tmx);
  split2h(ty, thy, tmy);
  split2h(tz, thz, tmz);
  u32x2 areg;
  if (kb == 0)      { areg = (u32x2){pkh(thx, thx), pkh(tmx, tmx)}; }
  else if (kb == 1) { areg = (u32x2){pkh(thy, thy), pkh(tmy, tmy)}; }
  else if (kb == 2) { areg = (u32x2){pkh(thz, thz), pkh(tmz, tmz)}; }
  else              { areg = (u32x2){pkh(1.f, 1.f), pkh(1.f, 0.f)}; }
  const f16x4 afrag = __builtin_bit_cast(f16x4, areg);
  const float Bv = -HKS * (tx * tx + ty * ty + tz * tz);
  // this lane's 4 output rows' B values (wave-lane constant)
  const float Bq0 = __shfl(Bv, kb * 4 + 0);
  const float Bq1 = __shfl(Bv, kb * 4 + 1);
  const float Bq2 = __shfl(Bv, kb * 4 + 2);
  const float Bq3 = __shfl(Bv, kb * 4 + 3);

  // running merged state (on-the-fly phase merge: 5 regs, not 10)
  float Mx = -1e30f;
  float r0 = 0.f, r1 = 0.f, r2 = 0.f, r3 = 0.f;

  #pragma unroll
  for (int h2 = 0; h2 < 2; ++h2) {
    // ---- stage 512 sources of this phase ----
    float am = -1e30f;
    #pragma unroll
    for (int i = 0; i < PH / THREADS; ++i) {
      int jl = tid + THREADS * i;
      int jg = 1024 * h + PH * h2 + jl;
      float A, q2;
      u32x4 pv;
      if constexpr (PRE) {
        pv = ps[jg];
        q2 = __uint_as_float(pv.w);
      } else {
        float sx = src[3 * jg + 0], sy = src[3 * jg + 1], sz = src[3 * jg + 2];
        q2 = HKS * (sx * sx + sy * sy + sz * sz);
        float shx, smx, shy, smy, shz, smz;
        split2h(KS * sx, shx, smx);
        split2h(KS * sy, shy, smy);
        split2h(KS * sz, shz, smz);
        pv = (u32x4){pkh(shx, smx), pkh(shy, smy), pkh(shz, smz), 0u};
      }
      if (t == 0) {
        A = -q2;
      } else {
        float m0 = pmA[(p * 2 + 0) * NPTS + jg];
        float m1 = pmA[(p * 2 + 1) * NPTS + jg];
        float c0 = psA[(p * 2 + 0) * NPTS + jg];
        float c1 = psA[(p * 2 + 1) * NPTS + jg];
        float M = fmaxf(m0, m1);
        float S = fmaf(c0, fexp2(m0 - M), c1 * fexp2(m1 - M));
        A = LOG2N - M - flog2(fmaxf(S, 1e-38f));   // = KS*phi_j - HKS|s_j|^2
      }
      am = fmaxf(am, A + q2);        // = KS*phi_j (t==0: exactly 0)
      float Ah, Am_, Al;
      split3h(A, Ah, Am_, Al);       // exact: A == Ah+Am_+Al
      Bfr[jl * 2 + 0] = (u32x4){pv.x, pv.x, pv.y, pv.y};               // kb0|kb1
      Bfr[jl * 2 + 1] = (u32x4){pv.z, pv.z, pkh(Ah, Am_), pkh(Al, 0.f)}; // kb2|kb3
    }
    #pragma unroll
    for (int off = 1; off <= 32; off <<= 1) am = fmaxf(am, __shfl_xor(am, off));
    if (lane == 0) wmax[wv] = am;
    __syncthreads();

    const float Amax = fmaxf(fmaxf(wmax[0], wmax[1]), fmaxf(wmax[2], wmax[3]));
    const f32x4 cin = {Bq0 - Amax, Bq1 - Amax, Bq2 - Amax, Bq3 - Amax};

    // ---- tile loop: 32 tiles of 16 sources; ds_read_b64 per lane ----
    const u32x2* bptr = (const u32x2*)Bfr + (l15 * 4 + kb);
    float s0 = 0.f, s1 = 0.f, s2 = 0.f, s3 = 0.f;
    #pragma unroll 4
    for (int tile = 0; tile < PH / 16; ++tile) {
      u32x2 braw = *bptr; bptr += 64;    // 16 sources x 4 u32x2 per tile
      f16x4 bfrag = __builtin_bit_cast(f16x4, braw);
      f32x4 d = mfma16x16x16(afrag, bfrag, cin);
      s0 += fexp2(d.x);
      s1 += fexp2(d.y);
      s2 += fexp2(d.z);
      s3 += fexp2(d.w);
    }

    // ---- reduce across the 16 col-lanes (same m̂ -> pure adds) ----
    #pragma unroll
    for (int off = 1; off <= 8; off <<= 1) {
      s0 += __shfl_xor(s0, off);
      s1 += __shfl_xor(s1, off);
      s2 += __shfl_xor(s2, off);
      s3 += __shfl_xor(s3, off);
    }

    // ---- on-the-fly merge (Amax diff is wave-uniform -> 2 exps) ----
    const float Mn = fmaxf(Mx, Amax);
    const float fo = fexp2(Mx - Amax > 0.f ? 0.f : Mx - Mn);   // exp2(Mx-Mn)
    const float fn = fexp2(Amax - Mn);
    r0 = fmaf(r0, fo, s0 * fn);
    r1 = fmaf(r1, fo, s1 * fn);
    r2 = fmaf(r2, fo, s2 * fn);
    r3 = fmaf(r3, fo, s3 * fn);
    Mx = Mn;
    __syncthreads();   // Bfr/wmax safe to overwrite next phase
  }

  // ---- store partials: m(row kb*4+q) = Mx - B_q ----
  if (l15 == 0) {
    float* om = omA + (p * 2 + h) * NPTS;
    float* os = osA + (p * 2 + h) * NPTS;
    int rr = rowbase + kb * 4;
    om[rr + 0] = Mx - Bq0; os[rr + 0] = r0;
    om[rr + 1] = Mx - Bq1; os[rr + 1] = r1;
    om[rr + 2] = Mx - Bq2; os[rr + 2] = r2;
    om[rr + 3] = Mx - Bq3; os[rr + 3] = r3;
  }
}

// Parallel finalize (round-9-proven, ns=2): 96 WGs x 256, deterministic
// double partials over the 98304 (side,problem,row) values.
__global__ void __launch_bounds__(256) sink_partial(
    const float* __restrict__ fm, const float* __restrict__ fs,
    const float* __restrict__ gm, const float* __restrict__ gs,
    const float* __restrict__ p1, const float* __restrict__ p2,
    double* __restrict__ part)
{
  __shared__ double wsum[4];
  const int tid = threadIdx.x;
  const int blk = blockIdx.x;
  const int PER_SIDE = NPROB * NPTS;     // 49152
  double acc = 0.0;
  #pragma unroll
  for (int k = 0; k < 4; ++k) {
    int idx = blk * 1024 + k * 256 + tid;
    int side = idx >= PER_SIDE;
    int rem  = idx - side * PER_SIDE;
    int p = rem >> 11;
    int i = rem & (NPTS - 1);
    const float* mA = side ? gm : fm;
    const float* sA = side ? gs : fs;
    float m0 = mA[(p * 2 + 0) * NPTS + i], m1 = mA[(p * 2 + 1) * NPTS + i];
    float c0 = sA[(p * 2 + 0) * NPTS + i], c1 = sA[(p * 2 + 1) * NPTS + i];
    float M = fmaxf(m0, m1);
    float S = fmaf(c0, fexp2(m0 - M), c1 * fexp2(m1 - M));
    int b = p / 3, kd = p - 3 * b;
    const float* rows = side ? (kd == 1 ? p1 : p2) : (kd == 2 ? p2 : p1);
    const float* pt = rows + b * (NPTS * 3) + 3 * i;
    float B = -HKS * (pt[0] * pt[0] + pt[1] * pt[1] + pt[2] * pt[2]);
    float val = NEG_EPS_LN2 * (M + B + flog2(fmaxf(S, 1e-38f)) - LOG2N);
    double wgt = (kd == 0) ? 1.0 : -0.5;
    acc += wgt * (double)val;
  }
  #pragma unroll
  for (int off = 1; off <= 32; off <<= 1) acc += __shfl_xor(acc, off);
  if ((tid & 63) == 0) wsum[tid >> 6] = acc;
  __syncthreads();
  if (tid == 0) part[blk] = ((wsum[0] + wsum[1]) + (wsum[2] + wsum[3]));
}

// Stage 2: one wave reduces the 96 partials.
__global__ void __launch_bounds__(64) sink_reduce(
    const double* __restrict__ part, float* __restrict__ out)
{
  const int tid = threadIdx.x;
  double acc = part[tid] + (tid < 32 ? part[64 + tid] : 0.0);
  #pragma unroll
  for (int off = 1; off <= 32; off <<= 1) acc += __shfl_xor(acc, off);
  if (tid == 0) out[0] = (float)(acc / (8.0 * 2048.0));
}

extern "C" void kernel_launch(void* const* d_in, const int* in_sizes, int n_in,
                              void* d_out, int out_size, void* d_ws, size_t ws_size,
                              hipStream_t stream)
{
  const float* p1 = (const float*)d_in[0];   // pcs1 [8,2048,3] f32
  const float* p2 = (const float*)d_in[1];   // pcs2 [8,2048,3] f32
  // workspace: 4 arrays of [24][2][2048] floats (m,s half-partials for f,g)
  // = 1.573 MB + 96 doubles + (optional) 16x2048 u32x4 precomp = 0.524 MB.
  const size_t elems = (size_t)NPROB * 2 * NPTS;
  float* fm = (float*)d_ws;
  float* fs = fm + elems;
  float* gm = fs + elems;
  float* gs = gm + elems;
  double* part = (double*)(gs + elems);
  u32x4* pre = (u32x4*)(part + 96);
  const size_t need_pre =
      4 * elems * sizeof(float) + 96 * sizeof(double) +
      (size_t)16 * NPTS * sizeof(u32x4);
  const bool use_pre = ws_size >= need_pre;

  if (use_pre) {
    sink_prep<<<dim3(128), dim3(256), 0, stream>>>(p1, p2, pre);
    for (int t = 0; t < NPASS; ++t)
      sink_mfma<true><<<dim3(NPROB * 64), dim3(THREADS), 0, stream>>>(
          p1, p2, fm, fs, gm, gs, pre, t);
  } else {
    for (int t = 0; t < NPASS; ++t)
      sink_mfma<false><<<dim3(NPROB * 64), dim3(THREADS), 0, stream>>>(
          p1, p2, fm, fs, gm, gs, pre, t);
  }
  sink_partial<<<dim3(96), dim3(256), 0, stream>>>(fm, fs, gm, gs, p1, p2, part);
  sink_reduce<<<dim3(1), dim3(64), 0, stream>>>(part, (float*)d_out);
}

// Round 13
// 1705.067 us; speedup vs baseline: 1.4515x; 1.1085x over previous
//
#include <hip/hip_runtime.h>

#ifndef __has_builtin
#define __has_builtin(x) 0
#endif

__device__ __forceinline__ float fexp2(float x) {
#if __has_builtin(__builtin_amdgcn_exp2f)
  return __builtin_amdgcn_exp2f(x);   // v_exp_f32 (2^x)
#else
  return exp2f(x);
#endif
}
__device__ __forceinline__ float flog2(float x) {
#if __has_builtin(__builtin_amdgcn_logf)
  return __builtin_amdgcn_logf(x);    // v_log_f32 (log2)
#else
  return log2f(x);
#endif
}

typedef float    f32x4 __attribute__((ext_vector_type(4)));
typedef unsigned int u32x2 __attribute__((ext_vector_type(2)));
typedef unsigned int u32x4 __attribute__((ext_vector_type(4)));
typedef _Float16 f16x4 __attribute__((ext_vector_type(4)));

__device__ __forceinline__ f32x4 mfma16x16x16(f16x4 a, f16x4 b, f32x4 c) {
#if __has_builtin(__builtin_amdgcn_mfma_f32_16x16x16_f16)
  return __builtin_amdgcn_mfma_f32_16x16x16_f16(a, b, c, 0, 0, 0);
#else
  return __builtin_amdgcn_mfma_f32_16x16x16f16(a, b, c, 0, 0, 0);
#endif
}

namespace {
constexpr int NPTS = 2048;
constexpr int NPROB = 24;           // 8 batches x {xy, xx, yy}
constexpr int THREADS = 512;        // 8 waves x 16 rows each (round-13: was 256)
constexpr int NPASS = 100;          // 50 Sinkhorn iters x 2 half-passes
constexpr int PH = 512;             // sources staged per phase (2 phases/WG)
constexpr float KS  = 1.44269504088896340736f / 0.0025f;   // log2(e)/eps
constexpr float HKS = 0.5f * KS;
constexpr float NEG_EPS_LN2 = -0.0025f * 0.69314718055994530942f; // -eps*ln2
constexpr float LOG2N = 11.0f;                             // log2(2048)
}

// 2-way f16 split: v ~= h + m, residual <= 2^-24|v| (dropped).
__device__ __forceinline__ void split2h(float v, float& h, float& m) {
  h = (float)(_Float16)v;
  m = (float)(_Float16)(v - h);
}
// 3-way f16 split: v == h + m + l EXACTLY (11+11+2 bits cover f32's 24).
__device__ __forceinline__ void split3h(float v, float& h, float& m, float& l) {
  h = (float)(_Float16)v;
  float r1 = v - h;
  m = (float)(_Float16)r1;
  l = r1 - m;
}
// pack two f32 as f16 into one VGPR: a -> k-even (low16), b -> k-odd.
__device__ __forceinline__ unsigned pkh(float a, float b) {
  unsigned short ab = __builtin_bit_cast(unsigned short, (_Float16)a);
  unsigned short bb = __builtin_bit_cast(unsigned short, (_Float16)b);
  return (unsigned)ab | ((unsigned)bb << 16);
}

// One-time prep: per (batch,cloud) point set (16 sets of 2048), precompute the
// pass-invariant source data: packed f16 splits of KS*s (wx,wy,wz) and
// q2 = HKS|s|^2, as one u32x4/source.
__global__ void __launch_bounds__(256) sink_prep(
    const float* __restrict__ p1, const float* __restrict__ p2,
    u32x4* __restrict__ pre)
{
  const int g = blockIdx.x;          // 0..127
  const int set = g >> 3;            // 0..15: 0-7 = p1 batches, 8-15 = p2
  const int j = (g & 7) * 256 + threadIdx.x;
  const float* src = (set < 8) ? p1 + set * (NPTS * 3)
                               : p2 + (set - 8) * (NPTS * 3);
  float sx = src[3 * j + 0], sy = src[3 * j + 1], sz = src[3 * j + 2];
  float q2 = HKS * (sx * sx + sy * sy + sz * sz);
  float shx, smx, shy, smy, shz, smz;
  split2h(KS * sx, shx, smx);
  split2h(KS * sy, shy, smy);
  split2h(KS * sz, shz, smz);
  pre[set * NPTS + j] =
      (u32x4){pkh(shx, smx), pkh(shy, smy), pkh(shz, smz), __float_as_uint(q2)};
}

// MFMA pass (round-13: 512-thread WGs). WG (p, blk, h): 128 target rows
// (8 waves x 16), partial LSE over sources j in [1024h, 1024h+1024), staged
// in two sequential 512-source phases (16 KB LDS buffer reused).
//   grid 768 -> 3 WG/CU (24 waves/CU, 6/SIMD — same wave count as round 12
//   but: staging 1 src/thread/phase (was 2), 16x problem-level staging
//   redundancy (was 32x), half the WG dispatches, 3 barriers/pass (was 4),
//   single deferred lane-reduction after the per-lane phase merge.
// Math (round-8/9-proven, bit-compatible): exp-arg(r,j) = t_r.(KS*s_j) + A_j
//   + B_r - Amax_ph; A_j = KS*phi_j - HKS|s_j|^2; B_r = -HKS|t_r|^2.
//   mfma_f32_16x16x16_f16, 15 slots: kb0/1/2 = x/y/z {th*sh,th*sm,tm*sh,
//   tm*sm}, kb3 = 1*{Ah,Am,Al} (A exact 3-way).
// Stored partials (NS=2 contract): m = Mx - B_r, s; LSE_part = m + log2 s + B_r.
template <bool PRE>
__global__ void __launch_bounds__(THREADS, 6) sink_mfma(
    const float* __restrict__ p1, const float* __restrict__ p2,
    float* __restrict__ fm, float* __restrict__ fs,
    float* __restrict__ gm, float* __restrict__ gs,
    const u32x4* __restrict__ pre, int t)
{
  __shared__ u32x4 Bfr[PH * 2];     // 16384 B: one 512-source frag buffer
  __shared__ float wmax[8];

  const int w   = blockIdx.x;
  const int p   = w >> 5;           // problem 0..23
  const int r_  = w & 31;
  const int blk = r_ & 15;          // row-block (128 rows)
  const int h   = r_ >> 4;          // source half 0/1
  const int b    = p / 3;
  const int kind = p - 3 * b;       // 0: xy, 1: xx, 2: yy
  const float* X = (kind == 2 ? p2 : p1) + b * (NPTS * 3);
  const float* Y = (kind == 1 ? p1 : p2) + b * (NPTS * 3);

  const bool even = (t & 1) == 0;
  const float* tgt = even ? X : Y;
  const float* src = even ? Y : X;
  const int sset = even ? (kind == 1 ? b : 8 + b) : (kind == 2 ? 8 + b : b);
  const u32x4* ps = pre + sset * NPTS;
  const float* pmA = even ? gm : fm;
  const float* psA = even ? gs : fs;
  float* omA = even ? fm : gm;
  float* osA = even ? fs : gs;

  const int tid  = threadIdx.x;
  const int lane = tid & 63;
  const int wv   = tid >> 6;        // wave 0..7
  const int l15  = lane & 15;
  const int kb   = lane >> 4;       // k-block this lane supplies

  // ---- per-lane A-frag: RAW target coords, 2-way split (once) ----
  const int rowbase = blk * 128 + wv * 16;
  const int r = rowbase + l15;
  float tx = tgt[3 * r + 0], ty = tgt[3 * r + 1], tz = tgt[3 * r + 2];
  float thx, tmx, thy, tmy, thz, tmz;
  split2h(tx, thx, tmx);
  split2h(ty, thy, tmy);
  split2h(tz, thz, tmz);
  u32x2 areg;
  if (kb == 0)      { areg = (u32x2){pkh(thx, thx), pkh(tmx, tmx)}; }
  else if (kb == 1) { areg = (u32x2){pkh(thy, thy), pkh(tmy, tmy)}; }
  else if (kb == 2) { areg = (u32x2){pkh(thz, thz), pkh(tmz, tmz)}; }
  else              { areg = (u32x2){pkh(1.f, 1.f), pkh(1.f, 0.f)}; }
  const f16x4 afrag = __builtin_bit_cast(f16x4, areg);
  const float Bv = -HKS * (tx * tx + ty * ty + tz * tz);
  const float Bq0 = __shfl(Bv, kb * 4 + 0);
  const float Bq1 = __shfl(Bv, kb * 4 + 1);
  const float Bq2 = __shfl(Bv, kb * 4 + 2);
  const float Bq3 = __shfl(Bv, kb * 4 + 3);

  // running merged per-lane state (lane-reduction deferred to the end)
  float Mx = -1e30f;
  float r0 = 0.f, r1 = 0.f, r2 = 0.f, r3 = 0.f;

  #pragma unroll
  for (int h2 = 0; h2 < 2; ++h2) {
    if (h2 == 1) __syncthreads();    // tiles of phase 0 done before restage
    // ---- stage this phase's 512 sources: 1 per thread ----
    {
      int jl = tid;
      int jg = 1024 * h + PH * h2 + jl;
      float A, q2;
      u32x4 pv;
      if constexpr (PRE) {
        pv = ps[jg];
        q2 = __uint_as_float(pv.w);
      } else {
        float sx = src[3 * jg + 0], sy = src[3 * jg + 1], sz = src[3 * jg + 2];
        q2 = HKS * (sx * sx + sy * sy + sz * sz);
        float shx, smx, shy, smy, shz, smz;
        split2h(KS * sx, shx, smx);
        split2h(KS * sy, shy, smy);
        split2h(KS * sz, shz, smz);
        pv = (u32x4){pkh(shx, smx), pkh(shy, smy), pkh(shz, smz), 0u};
      }
      if (t == 0) {
        A = -q2;
      } else {
        float m0 = pmA[(p * 2 + 0) * NPTS + jg];
        float m1 = pmA[(p * 2 + 1) * NPTS + jg];
        float c0 = psA[(p * 2 + 0) * NPTS + jg];
        float c1 = psA[(p * 2 + 1) * NPTS + jg];
        float M = fmaxf(m0, m1);
        float S = fmaf(c0, fexp2(m0 - M), c1 * fexp2(m1 - M));
        A = LOG2N - M - flog2(fmaxf(S, 1e-38f));   // = KS*phi_j - HKS|s_j|^2
      }
      float am = A + q2;             // = KS*phi_j (t==0: exactly 0)
      float Ah, Am_, Al;
      split3h(A, Ah, Am_, Al);       // exact: A == Ah+Am_+Al
      Bfr[jl * 2 + 0] = (u32x4){pv.x, pv.x, pv.y, pv.y};               // kb0|kb1
      Bfr[jl * 2 + 1] = (u32x4){pv.z, pv.z, pkh(Ah, Am_), pkh(Al, 0.f)}; // kb2|kb3
      #pragma unroll
      for (int off = 1; off <= 32; off <<= 1)
        am = fmaxf(am, __shfl_xor(am, off));
      if (lane == 0) wmax[wv] = am;
    }
    __syncthreads();

    const float Amax =
        fmaxf(fmaxf(fmaxf(wmax[0], wmax[1]), fmaxf(wmax[2], wmax[3])),
              fmaxf(fmaxf(wmax[4], wmax[5]), fmaxf(wmax[6], wmax[7])));
    const f32x4 cin = {Bq0 - Amax, Bq1 - Amax, Bq2 - Amax, Bq3 - Amax};

    // ---- tile loop: 32 tiles of 16 sources; ds_read_b64 per lane ----
    const u32x2* bptr = (const u32x2*)Bfr + (l15 * 4 + kb);
    float s0 = 0.f, s1 = 0.f, s2 = 0.f, s3 = 0.f;
    #pragma unroll 4
    for (int tile = 0; tile < PH / 16; ++tile) {
      u32x2 braw = *bptr; bptr += 64;    // 16 sources x 4 u32x2 per tile
      f16x4 bfrag = __builtin_bit_cast(f16x4, braw);
      f32x4 d = mfma16x16x16(afrag, bfrag, cin);
      s0 += fexp2(d.x);
      s1 += fexp2(d.y);
      s2 += fexp2(d.z);
      s3 += fexp2(d.w);
    }

    // ---- per-lane phase merge (Amax diff wave-uniform -> 2 exps) ----
    const float Mn = fmaxf(Mx, Amax);
    const float fo = fexp2(Mx - Mn);
    const float fn = fexp2(Amax - Mn);
    r0 = fmaf(r0, fo, s0 * fn);
    r1 = fmaf(r1, fo, s1 * fn);
    r2 = fmaf(r2, fo, s2 * fn);
    r3 = fmaf(r3, fo, s3 * fn);
    Mx = Mn;
  }

  // ---- single deferred reduce across the 16 col-lanes (pure adds) ----
  #pragma unroll
  for (int off = 1; off <= 8; off <<= 1) {
    r0 += __shfl_xor(r0, off);
    r1 += __shfl_xor(r1, off);
    r2 += __shfl_xor(r2, off);
    r3 += __shfl_xor(r3, off);
  }

  // ---- store partials: m(row kb*4+q) = Mx - B_q ----
  if (l15 == 0) {
    float* om = omA + (p * 2 + h) * NPTS;
    float* os = osA + (p * 2 + h) * NPTS;
    int rr = rowbase + kb * 4;
    om[rr + 0] = Mx - Bq0; os[rr + 0] = r0;
    om[rr + 1] = Mx - Bq1; os[rr + 1] = r1;
    om[rr + 2] = Mx - Bq2; os[rr + 2] = r2;
    om[rr + 3] = Mx - Bq3; os[rr + 3] = r3;
  }
}

// Parallel finalize (round-9-proven, ns=2): 96 WGs x 256, deterministic
// double partials over the 98304 (side,problem,row) values.
__global__ void __launch_bounds__(256) sink_partial(
    const float* __restrict__ fm, const float* __restrict__ fs,
    const float* __restrict__ gm, const float* __restrict__ gs,
    const float* __restrict__ p1, const float* __restrict__ p2,
    double* __restrict__ part)
{
  __shared__ double wsum[4];
  const int tid = threadIdx.x;
  const int blk = blockIdx.x;
  const int PER_SIDE = NPROB * NPTS;     // 49152
  double acc = 0.0;
  #pragma unroll
  for (int k = 0; k < 4; ++k) {
    int idx = blk * 1024 + k * 256 + tid;
    int side = idx >= PER_SIDE;
    int rem  = idx - side * PER_SIDE;
    int p = rem >> 11;
    int i = rem & (NPTS - 1);
    const float* mA = side ? gm : fm;
    const float* sA = side ? gs : fs;
    float m0 = mA[(p * 2 + 0) * NPTS + i], m1 = mA[(p * 2 + 1) * NPTS + i];
    float c0 = sA[(p * 2 + 0) * NPTS + i], c1 = sA[(p * 2 + 1) * NPTS + i];
    float M = fmaxf(m0, m1);
    float S = fmaf(c0, fexp2(m0 - M), c1 * fexp2(m1 - M));
    int b = p / 3, kd = p - 3 * b;
    const float* rows = side ? (kd == 1 ? p1 : p2) : (kd == 2 ? p2 : p1);
    const float* pt = rows + b * (NPTS * 3) + 3 * i;
    float B = -HKS * (pt[0] * pt[0] + pt[1] * pt[1] + pt[2] * pt[2]);
    float val = NEG_EPS_LN2 * (M + B + flog2(fmaxf(S, 1e-38f)) - LOG2N);
    double wgt = (kd == 0) ? 1.0 : -0.5;
    acc += wgt * (double)val;
  }
  #pragma unroll
  for (int off = 1; off <= 32; off <<= 1) acc += __shfl_xor(acc, off);
  if ((tid & 63) == 0) wsum[tid >> 6] = acc;
  __syncthreads();
  if (tid == 0) part[blk] = ((wsum[0] + wsum[1]) + (wsum[2] + wsum[3]));
}

// Stage 2: one wave reduces the 96 partials.
__global__ void __launch_bounds__(64) sink_reduce(
    const double* __restrict__ part, float* __restrict__ out)
{
  const int tid = threadIdx.x;
  double acc = part[tid] + (tid < 32 ? part[64 + tid] : 0.0);
  #pragma unroll
  for (int off = 1; off <= 32; off <<= 1) acc += __shfl_xor(acc, off);
  if (tid == 0) out[0] = (float)(acc / (8.0 * 2048.0));
}

extern "C" void kernel_launch(void* const* d_in, const int* in_sizes, int n_in,
                              void* d_out, int out_size, void* d_ws, size_t ws_size,
                              hipStream_t stream)
{
  const float* p1 = (const float*)d_in[0];   // pcs1 [8,2048,3] f32
  const float* p2 = (const float*)d_in[1];   // pcs2 [8,2048,3] f32
  const size_t elems = (size_t)NPROB * 2 * NPTS;
  float* fm = (float*)d_ws;
  float* fs = fm + elems;
  float* gm = fs + elems;
  float* gs = gm + elems;
  double* part = (double*)(gs + elems);
  u32x4* pre = (u32x4*)(part + 96);
  const size_t need_pre =
      4 * elems * sizeof(float) + 96 * sizeof(double) +
      (size_t)16 * NPTS * sizeof(u32x4);
  const bool use_pre = ws_size >= need_pre;

  if (use_pre) {
    sink_prep<<<dim3(128), dim3(256), 0, stream>>>(p1, p2, pre);
    for (int t = 0; t < NPASS; ++t)
      sink_mfma<true><<<dim3(NPROB * 32), dim3(THREADS), 0, stream>>>(
          p1, p2, fm, fs, gm, gs, pre, t);
  } else {
    for (int t = 0; t < NPASS; ++t)
      sink_mfma<false><<<dim3(NPROB * 32), dim3(THREADS), 0, stream>>>(
          p1, p2, fm, fs, gm, gs, pre, t);
  }
  sink_partial<<<dim3(96), dim3(256), 0, stream>>>(fm, fs, gm, gs, p1, p2, part);
  sink_reduce<<<dim3(1), dim3(64), 0, stream>>>(part, (float*)d_out);
}

// Round 14
// 1647.276 us; speedup vs baseline: 1.5025x; 1.0351x over previous
//
#include <hip/hip_runtime.h>

#ifndef __has_builtin
#define __has_builtin(x) 0
#endif

__device__ __forceinline__ float fexp2(float x) {
#if __has_builtin(__builtin_amdgcn_exp2f)
  return __builtin_amdgcn_exp2f(x);   // v_exp_f32 (2^x)
#else
  return exp2f(x);
#endif
}
__device__ __forceinline__ float flog2(float x) {
#if __has_builtin(__builtin_amdgcn_logf)
  return __builtin_amdgcn_logf(x);    // v_log_f32 (log2)
#else
  return log2f(x);
#endif
}

typedef float    f32x4 __attribute__((ext_vector_type(4)));
typedef unsigned int u32x2 __attribute__((ext_vector_type(2)));
typedef unsigned int u32x4 __attribute__((ext_vector_type(4)));
typedef _Float16 f16x4 __attribute__((ext_vector_type(4)));

__device__ __forceinline__ f32x4 mfma16x16x16(f16x4 a, f16x4 b, f32x4 c) {
#if __has_builtin(__builtin_amdgcn_mfma_f32_16x16x16_f16)
  return __builtin_amdgcn_mfma_f32_16x16x16_f16(a, b, c, 0, 0, 0);
#else
  return __builtin_amdgcn_mfma_f32_16x16x16f16(a, b, c, 0, 0, 0);
#endif
}

namespace {
constexpr int NPTS = 2048;
constexpr int NPROB = 24;           // 8 batches x {xy, xx, yy}
constexpr int THREADS = 512;        // 8 waves x 16 rows each
constexpr int NPASS = 100;          // 50 Sinkhorn iters x 2 half-passes
constexpr int HALF = 1024;          // sources per WG (round-14: one phase)
constexpr float KS  = 1.44269504088896340736f / 0.0025f;   // log2(e)/eps
constexpr float HKS = 0.5f * KS;
constexpr float NEG_EPS_LN2 = -0.0025f * 0.69314718055994530942f; // -eps*ln2
constexpr float LOG2N = 11.0f;                             // log2(2048)
}

// 2-way f16 split: v ~= h + m, residual <= 2^-24|v| (dropped).
__device__ __forceinline__ void split2h(float v, float& h, float& m) {
  h = (float)(_Float16)v;
  m = (float)(_Float16)(v - h);
}
// 3-way f16 split: v == h + m + l EXACTLY (11+11+2 bits cover f32's 24).
__device__ __forceinline__ void split3h(float v, float& h, float& m, float& l) {
  h = (float)(_Float16)v;
  float r1 = v - h;
  m = (float)(_Float16)r1;
  l = r1 - m;
}
// pack two f32 as f16 into one VGPR: a -> k-even (low16), b -> k-odd.
__device__ __forceinline__ unsigned pkh(float a, float b) {
  unsigned short ab = __builtin_bit_cast(unsigned short, (_Float16)a);
  unsigned short bb = __builtin_bit_cast(unsigned short, (_Float16)b);
  return (unsigned)ab | ((unsigned)bb << 16);
}

// One-time prep: per (batch,cloud) point set (16 sets of 2048), precompute the
// pass-invariant source data: packed f16 splits of KS*s (wx,wy,wz) and
// q2 = HKS|s|^2, as one u32x4/source.
__global__ void __launch_bounds__(256) sink_prep(
    const float* __restrict__ p1, const float* __restrict__ p2,
    u32x4* __restrict__ pre)
{
  const int g = blockIdx.x;          // 0..127
  const int set = g >> 3;            // 0..15: 0-7 = p1 batches, 8-15 = p2
  const int j = (g & 7) * 256 + threadIdx.x;
  const float* src = (set < 8) ? p1 + set * (NPTS * 3)
                               : p2 + (set - 8) * (NPTS * 3);
  float sx = src[3 * j + 0], sy = src[3 * j + 1], sz = src[3 * j + 2];
  float q2 = HKS * (sx * sx + sy * sy + sz * sz);
  float shx, smx, shy, smy, shz, smz;
  split2h(KS * sx, shx, smx);
  split2h(KS * sy, shy, smy);
  split2h(KS * sz, shz, smz);
  pre[set * NPTS + j] =
      (u32x4){pkh(shx, smx), pkh(shy, smy), pkh(shz, smz), __float_as_uint(q2)};
}

// MFMA pass (round-14: single phase). WG (p, blk, h): 128 target rows
// (8 waves x 16), partial LSE over ALL 1024 sources of half h, staged once
// into a 32 KB LDS buffer. grid 768 -> 3 WG/CU (LDS cap 4, wave cap 3) ->
// single-generation residency, 6 waves/SIMD. ONE barrier per pass (was 3);
// no phase-merge VALU; staging loads (2 src/thread + 8 partial floats)
// issued in one upfront burst so HBM/L2 latency is paid once.
// Math (round-8/9-proven, bit-compatible): exp-arg(r,j) = t_r.(KS*s_j) + A_j
//   + B_r - Amax; A_j = KS*phi_j - HKS|s_j|^2; B_r = -HKS|t_r|^2;
//   Amax = max over the 1024 staged sources of KS*phi_j (identical value to
//   round 13's two-phase merged Mx). mfma_f32_16x16x16_f16, 15 slots:
//   kb0/1/2 = x/y/z {th*sh,th*sm,tm*sh,tm*sm}, kb3 = 1*{Ah,Am,Al} (A exact).
// Stored partials (NS=2 contract): m = Amax - B_r, s; LSE_part = m + log2 s + B_r.
template <bool PRE>
__global__ void __launch_bounds__(THREADS, 3) sink_mfma(
    const float* __restrict__ p1, const float* __restrict__ p2,
    float* __restrict__ fm, float* __restrict__ fs,
    float* __restrict__ gm, float* __restrict__ gs,
    const u32x4* __restrict__ pre, int t)
{
  __shared__ u32x4 Bfr[HALF * 2];   // 32768 B: all 1024 sources staged once
  __shared__ float wmax[8];

  const int w   = blockIdx.x;
  const int p   = w >> 5;           // problem 0..23
  const int r_  = w & 31;
  const int blk = r_ & 15;          // row-block (128 rows)
  const int h   = r_ >> 4;          // source half 0/1
  const int b    = p / 3;
  const int kind = p - 3 * b;       // 0: xy, 1: xx, 2: yy
  const float* X = (kind == 2 ? p2 : p1) + b * (NPTS * 3);
  const float* Y = (kind == 1 ? p1 : p2) + b * (NPTS * 3);

  const bool even = (t & 1) == 0;
  const float* tgt = even ? X : Y;
  const float* src = even ? Y : X;
  const int sset = even ? (kind == 1 ? b : 8 + b) : (kind == 2 ? 8 + b : b);
  const u32x4* ps = pre + sset * NPTS;
  const float* pmA = even ? gm : fm;
  const float* psA = even ? gs : fs;
  float* omA = even ? fm : gm;
  float* osA = even ? fs : gs;

  const int tid  = threadIdx.x;
  const int lane = tid & 63;
  const int wv   = tid >> 6;        // wave 0..7
  const int l15  = lane & 15;
  const int kb   = lane >> 4;       // k-block this lane supplies

  // ---- stage all 1024 sources: 2 per thread, loads issued upfront ----
  float am = -1e30f;
  #pragma unroll
  for (int i = 0; i < HALF / THREADS; ++i) {
    int jl = tid + THREADS * i;
    int jg = HALF * h + jl;
    float A, q2;
    u32x4 pv;
    if constexpr (PRE) {
      pv = ps[jg];
      q2 = __uint_as_float(pv.w);
    } else {
      float sx = src[3 * jg + 0], sy = src[3 * jg + 1], sz = src[3 * jg + 2];
      q2 = HKS * (sx * sx + sy * sy + sz * sz);
      float shx, smx, shy, smy, shz, smz;
      split2h(KS * sx, shx, smx);
      split2h(KS * sy, shy, smy);
      split2h(KS * sz, shz, smz);
      pv = (u32x4){pkh(shx, smx), pkh(shy, smy), pkh(shz, smz), 0u};
    }
    if (t == 0) {
      A = -q2;
    } else {
      float m0 = pmA[(p * 2 + 0) * NPTS + jg];
      float m1 = pmA[(p * 2 + 1) * NPTS + jg];
      float c0 = psA[(p * 2 + 0) * NPTS + jg];
      float c1 = psA[(p * 2 + 1) * NPTS + jg];
      float M = fmaxf(m0, m1);
      float S = fmaf(c0, fexp2(m0 - M), c1 * fexp2(m1 - M));
      A = LOG2N - M - flog2(fmaxf(S, 1e-38f));   // = KS*phi_j - HKS|s_j|^2
    }
    am = fmaxf(am, A + q2);          // = KS*phi_j (t==0: exactly 0)
    float Ah, Am_, Al;
    split3h(A, Ah, Am_, Al);         // exact: A == Ah+Am_+Al
    Bfr[jl * 2 + 0] = (u32x4){pv.x, pv.x, pv.y, pv.y};                 // kb0|kb1
    Bfr[jl * 2 + 1] = (u32x4){pv.z, pv.z, pkh(Ah, Am_), pkh(Al, 0.f)}; // kb2|kb3
  }
  #pragma unroll
  for (int off = 1; off <= 32; off <<= 1) am = fmaxf(am, __shfl_xor(am, off));
  if (lane == 0) wmax[wv] = am;

  // ---- per-lane A-frag: RAW target coords, 2-way split ----
  const int rowbase = blk * 128 + wv * 16;
  const int r = rowbase + l15;
  float tx = tgt[3 * r + 0], ty = tgt[3 * r + 1], tz = tgt[3 * r + 2];
  float thx, tmx, thy, tmy, thz, tmz;
  split2h(tx, thx, tmx);
  split2h(ty, thy, tmy);
  split2h(tz, thz, tmz);
  u32x2 areg;
  if (kb == 0)      { areg = (u32x2){pkh(thx, thx), pkh(tmx, tmx)}; }
  else if (kb == 1) { areg = (u32x2){pkh(thy, thy), pkh(tmy, tmy)}; }
  else if (kb == 2) { areg = (u32x2){pkh(thz, thz), pkh(tmz, tmz)}; }
  else              { areg = (u32x2){pkh(1.f, 1.f), pkh(1.f, 0.f)}; }
  const f16x4 afrag = __builtin_bit_cast(f16x4, areg);
  const float Bv = -HKS * (tx * tx + ty * ty + tz * tz);
  const float Bq0 = __shfl(Bv, kb * 4 + 0);
  const float Bq1 = __shfl(Bv, kb * 4 + 1);
  const float Bq2 = __shfl(Bv, kb * 4 + 2);
  const float Bq3 = __shfl(Bv, kb * 4 + 3);

  __syncthreads();                  // the pass's single barrier

  const float Amax =
      fmaxf(fmaxf(fmaxf(wmax[0], wmax[1]), fmaxf(wmax[2], wmax[3])),
            fmaxf(fmaxf(wmax[4], wmax[5]), fmaxf(wmax[6], wmax[7])));
  const f32x4 cin = {Bq0 - Amax, Bq1 - Amax, Bq2 - Amax, Bq3 - Amax};

  // ---- tile loop: 64 tiles of 16 sources; ds_read_b64 per lane ----
  const u32x2* bptr = (const u32x2*)Bfr + (l15 * 4 + kb);
  float r0 = 0.f, r1 = 0.f, r2 = 0.f, r3 = 0.f;
  #pragma unroll 4
  for (int tile = 0; tile < HALF / 16; ++tile) {
    u32x2 braw = *bptr; bptr += 64;    // 16 sources x 4 u32x2 per tile
    f16x4 bfrag = __builtin_bit_cast(f16x4, braw);
    f32x4 d = mfma16x16x16(afrag, bfrag, cin);
    r0 += fexp2(d.x);
    r1 += fexp2(d.y);
    r2 += fexp2(d.z);
    r3 += fexp2(d.w);
  }

  // ---- reduce across the 16 col-lanes (same m̂ -> pure adds) ----
  #pragma unroll
  for (int off = 1; off <= 8; off <<= 1) {
    r0 += __shfl_xor(r0, off);
    r1 += __shfl_xor(r1, off);
    r2 += __shfl_xor(r2, off);
    r3 += __shfl_xor(r3, off);
  }

  // ---- store partials: m(row kb*4+q) = Amax - B_q ----
  if (l15 == 0) {
    float* om = omA + (p * 2 + h) * NPTS;
    float* os = osA + (p * 2 + h) * NPTS;
    int rr = rowbase + kb * 4;
    om[rr + 0] = Amax - Bq0; os[rr + 0] = r0;
    om[rr + 1] = Amax - Bq1; os[rr + 1] = r1;
    om[rr + 2] = Amax - Bq2; os[rr + 2] = r2;
    om[rr + 3] = Amax - Bq3; os[rr + 3] = r3;
  }
}

// Parallel finalize (round-9-proven, ns=2): 96 WGs x 256, deterministic
// double partials over the 98304 (side,problem,row) values.
__global__ void __launch_bounds__(256) sink_partial(
    const float* __restrict__ fm, const float* __restrict__ fs,
    const float* __restrict__ gm, const float* __restrict__ gs,
    const float* __restrict__ p1, const float* __restrict__ p2,
    double* __restrict__ part)
{
  __shared__ double wsum[4];
  const int tid = threadIdx.x;
  const int blk = blockIdx.x;
  const int PER_SIDE = NPROB * NPTS;     // 49152
  double acc = 0.0;
  #pragma unroll
  for (int k = 0; k < 4; ++k) {
    int idx = blk * 1024 + k * 256 + tid;
    int side = idx >= PER_SIDE;
    int rem  = idx - side * PER_SIDE;
    int p = rem >> 11;
    int i = rem & (NPTS - 1);
    const float* mA = side ? gm : fm;
    const float* sA = side ? gs : fs;
    float m0 = mA[(p * 2 + 0) * NPTS + i], m1 = mA[(p * 2 + 1) * NPTS + i];
    float c0 = sA[(p * 2 + 0) * NPTS + i], c1 = sA[(p * 2 + 1) * NPTS + i];
    float M = fmaxf(m0, m1);
    float S = fmaf(c0, fexp2(m0 - M), c1 * fexp2(m1 - M));
    int b = p / 3, kd = p - 3 * b;
    const float* rows = side ? (kd == 1 ? p1 : p2) : (kd == 2 ? p2 : p1);
    const float* pt = rows + b * (NPTS * 3) + 3 * i;
    float B = -HKS * (pt[0] * pt[0] + pt[1] * pt[1] + pt[2] * pt[2]);
    float val = NEG_EPS_LN2 * (M + B + flog2(fmaxf(S, 1e-38f)) - LOG2N);
    double wgt = (kd == 0) ? 1.0 : -0.5;
    acc += wgt * (double)val;
  }
  #pragma unroll
  for (int off = 1; off <= 32; off <<= 1) acc += __shfl_xor(acc, off);
  if ((tid & 63) == 0) wsum[tid >> 6] = acc;
  __syncthreads();
  if (tid == 0) part[blk] = ((wsum[0] + wsum[1]) + (wsum[2] + wsum[3]));
}

// Stage 2: one wave reduces the 96 partials.
__global__ void __launch_bounds__(64) sink_reduce(
    const double* __restrict__ part, float* __restrict__ out)
{
  const int tid = threadIdx.x;
  double acc = part[tid] + (tid < 32 ? part[64 + tid] : 0.0);
  #pragma unroll
  for (int off = 1; off <= 32; off <<= 1) acc += __shfl_xor(acc, off);
  if (tid == 0) out[0] = (float)(acc / (8.0 * 2048.0));
}

extern "C" void kernel_launch(void* const* d_in, const int* in_sizes, int n_in,
                              void* d_out, int out_size, void* d_ws, size_t ws_size,
                              hipStream_t stream)
{
  const float* p1 = (const float*)d_in[0];   // pcs1 [8,2048,3] f32
  const float* p2 = (const float*)d_in[1];   // pcs2 [8,2048,3] f32
  const size_t elems = (size_t)NPROB * 2 * NPTS;
  float* fm = (float*)d_ws;
  float* fs = fm + elems;
  float* gm = fs + elems;
  float* gs = gm + elems;
  double* part = (double*)(gs + elems);
  u32x4* pre = (u32x4*)(part + 96);
  const size_t need_pre =
      4 * elems * sizeof(float) + 96 * sizeof(double) +
      (size_t)16 * NPTS * sizeof(u32x4);
  const bool use_pre = ws_size >= need_pre;

  if (use_pre) {
    sink_prep<<<dim3(128), dim3(256), 0, stream>>>(p1, p2, pre);
    for (int t = 0; t < NPASS; ++t)
      sink_mfma<true><<<dim3(NPROB * 32), dim3(THREADS), 0, stream>>>(
          p1, p2, fm, fs, gm, gs, pre, t);
  } else {
    for (int t = 0; t < NPASS; ++t)
      sink_mfma<false><<<dim3(NPROB * 32), dim3(THREADS), 0, stream>>>(
          p1, p2, fm, fs, gm, gs, pre, t);
  }
  sink_partial<<<dim3(96), dim3(256), 0, stream>>>(fm, fs, gm, gs, p1, p2, part);
  sink_reduce<<<dim3(1), dim3(64), 0, stream>>>(part, (float*)d_out);
}